// Round 11
// baseline (237.782 us; speedup 1.0000x reference)
//
#include <hip/hip_runtime.h>
#include <hip/hip_bf16.h>
#include <math.h>

#define DIM 768
#define NHEADS 12
#define HD 64
#define SEQ 4096
#define KSPLIT 2

typedef __bf16 bf16x8 __attribute__((ext_vector_type(8)));
typedef float f32x4 __attribute__((ext_vector_type(4)));

// Native bf16 convert (RNE) — used outside flash.
__device__ inline ushort f2bf(float f) {
    __bf16 b = (__bf16)f;
    union { __bf16 b; ushort u; } v; v.b = b;
    return v.u;
}

// Manual RNE twiddle — used inside flash (unbiased RNE REQUIRED:
// v_cvt_pk_bf16_f32 biased P downward, failed absmax 4.3e-2 in round 1).
__device__ inline ushort f2bf_tw(float f) {
    union { float f; uint u; } v; v.f = f;
    uint r = v.u + 0x7FFF + ((v.u >> 16) & 1);
    return (ushort)(r >> 16);
}

// global -> LDS direct copy, 16B per lane. LDS dest is WAVE-UNIFORM base
// (hw adds lane*16); global src is per-lane.
__device__ inline void gload16(const ushort* gsrc, ushort* lbase) {
    __builtin_amdgcn_global_load_lds(
        (const __attribute__((address_space(1))) uint*)gsrc,
        (__attribute__((address_space(3))) uint*)lbase, 16, 0, 0);
}

// ---------------------------------------------------------------------------
// Fused prologue: block-range dispatch over
//   [0,3072)    : x f32 -> bf16            (4096*768 /4 /256)
//   [3072,4800) : qkv_w f32 -> bf16        (3*768*768 /4 /256)
//   [4800,5376) : proj_w f32 -> bf16       (768*768 /4 /256)
//   [5376,5888) : RoPE table tab[n][j]     (4096*32 /256)
// ---------------------------------------------------------------------------
__global__ __launch_bounds__(256)
void prep(const float* __restrict__ x, const float* __restrict__ qkv_w,
          const float* __restrict__ proj_w,
          ushort* __restrict__ xb, ushort* __restrict__ qwb,
          ushort* __restrict__ pwb, float2* __restrict__ tab)
{
    const int b = blockIdx.x;
    if (b < 5376) {
        const float* src; ushort* dst; int i;
        if (b < 3072)      { src = x;      dst = xb;  i = b * 256 + threadIdx.x; }
        else if (b < 4800) { src = qkv_w;  dst = qwb; i = (b - 3072) * 256 + threadIdx.x; }
        else               { src = proj_w; dst = pwb; i = (b - 4800) * 256 + threadIdx.x; }
        const float4 v = ((const float4*)src)[i];
        ushort4 w;
        w.x = f2bf(v.x); w.y = f2bf(v.y); w.z = f2bf(v.z); w.w = f2bf(v.w);
        ((ushort4*)dst)[i] = w;
    } else {
        const int idx = (b - 5376) * 256 + threadIdx.x;   // 4096*32
        const int j = idx & 31;
        const int n = idx >> 5;
        const float invf = (float)pow(10000.0, -(double)j / 32.0);
        const float ang  = (float)n * invf;               // f32 (matches ref freqs)
        double s, c;
        sincos((double)ang, &s, &c);
        tab[idx] = make_float2((float)c, (float)s);
    }
}

// ---------------------------------------------------------------------------
// QKV GEMM (bf16 in) + fused RoPE + layout. T3 1-barrier double-buffered
// K-loop. LDS 64 KB -> 2 blocks/CU.
//   t=0 (q): RoPE, *0.125*log2e (exp->exp2 fold), bf16 -> Qb[h][n][d]
//   t=1 (k): RoPE, bf16 -> Kb[h][n][d]
//   t=2 (v): bf16 -> Vp[h][d][64T + slot], slot permuted for the SWAPPED-
//            QK^T flash PV path: key kappa=16i+4quad+r -> slot
//            32*(i>>1) + 8*quad + 4*(i&1) + r  (so flash's in-register P
//            fragments [p(n=2c)[0..3], p(2c+1)[0..3]] multiply V directly).
// ---------------------------------------------------------------------------
__global__ __launch_bounds__(256)
void gemm_qkv(const ushort* __restrict__ A, const ushort* __restrict__ B,
              const float2* __restrict__ tab,
              ushort* __restrict__ Qb, ushort* __restrict__ Kb,
              ushort* __restrict__ Vp)
{
    constexpr int BM = 128, BN = 128, BK = 64;
    __shared__ __attribute__((aligned(16))) ushort Ah[2][BM][BK];
    __shared__ __attribute__((aligned(16))) ushort Bh[2][BN][BK];

    const int t    = threadIdx.x;
    const int lane = t & 63;
    const int wv   = t >> 6;
    const int wm   = (wv >> 1) * 64;
    const int wn   = (wv & 1) * 64;
    const int m0   = blockIdx.y * BM;
    const int n0   = blockIdx.x * BN;

    f32x4 acc[4][4] = {};

    const int lrow = lane >> 3;        // 0..7  row within 8-row wave stripe
    const int lch  = (lane & 7) * 8;   // 16B chunk (ushort offset)

    // prologue: stage k0=0 into buf 0
    #pragma unroll
    for (int i = 0; i < 4; ++i) {
        const int rb = i * 32 + wv * 8;          // wave-uniform row base
        gload16(&A[(size_t)(m0 + rb + lrow) * DIM + lch], &Ah[0][rb][0]);
        gload16(&B[(size_t)(n0 + rb + lrow) * DIM + lch], &Bh[0][rb][0]);
    }
    __syncthreads();

    int cur = 0;
    for (int k0 = 0; k0 < DIM; k0 += BK) {
        if (k0 + BK < DIM) {       // prefetch next K-tile into buf^1
            #pragma unroll
            for (int i = 0; i < 4; ++i) {
                const int rb = i * 32 + wv * 8;
                gload16(&A[(size_t)(m0 + rb + lrow) * DIM + k0 + BK + lch],
                        &Ah[cur ^ 1][rb][0]);
                gload16(&B[(size_t)(n0 + rb + lrow) * DIM + k0 + BK + lch],
                        &Bh[cur ^ 1][rb][0]);
            }
        }

        #pragma unroll
        for (int ks = 0; ks < BK; ks += 32) {
            const int koff = ks + ((lane >> 4) << 3);
            const int rs = lane & 15;
            bf16x8 af[4], bf[4];
            #pragma unroll
            for (int i = 0; i < 4; ++i) {
                af[i] = *(const bf16x8*)&Ah[cur][wm + i * 16 + rs][koff];
                bf[i] = *(const bf16x8*)&Bh[cur][wn + i * 16 + rs][koff];
            }
            #pragma unroll
            for (int i = 0; i < 4; ++i)
                #pragma unroll
                for (int j = 0; j < 4; ++j)
                    acc[i][j] = __builtin_amdgcn_mfma_f32_16x16x32_bf16(
                        af[i], bf[j], acc[i][j], 0, 0, 0);
        }
        __syncthreads();   // drains vmcnt (prefetch landed, hidden) + lgkm;
        cur ^= 1;          // all waves done reading old buf
    }

    const int rsel  = lane & 15;
    const int quad  = lane >> 4;
    const int rbase = m0 + wm + (quad << 2);
    const int c0    = n0 + wn;          // 64-aligned -> one (t,h) per wave
    const int tt    = c0 / DIM;
    const int h     = (c0 % DIM) >> 6;

    if (tt == 2) {
        // key kappa (within 64-tile) = 16i + 4quad + r
        // -> slot 32*(i>>1) + 8*quad + 4*(i&1) + r   (swapped-PV order)
        const int T = (m0 + wm) >> 6;
        #pragma unroll
        for (int j = 0; j < 4; ++j) {
            const int d = rsel + 16 * j;
            ushort vvA[8], vvB[8];
            #pragma unroll
            for (int i2 = 0; i2 < 2; ++i2)
                #pragma unroll
                for (int r = 0; r < 4; ++r) {
                    vvA[4 * i2 + r] = f2bf(acc[i2][j][r]);        // i=0,1 -> c=0
                    vvB[4 * i2 + r] = f2bf(acc[2 + i2][j][r]);    // i=2,3 -> c=1
                }
            ushort* dst = &Vp[((size_t)h * HD + d) * SEQ + T * 64];
            *(float4*)&dst[8 * quad]      = *(const float4*)&vvA[0];
            *(float4*)&dst[32 + 8 * quad] = *(const float4*)&vvB[0];
        }
    } else {
        ushort* dstb = (tt == 0 ? Qb : Kb) + (size_t)h * SEQ * HD;
        // 0.125 * log2(e): flash computes exp(S) via v_exp_f32 (2^S').
        const float qs = (tt == 0) ? 0.18033688011112042f : 1.0f;
        #pragma unroll
        for (int i = 0; i < 4; ++i)
            #pragma unroll
            for (int r = 0; r < 4; ++r) {
                const int n = rbase + i * 16 + r;
                #pragma unroll
                for (int j = 0; j < 2; ++j) {
                    const float a = acc[i][j][r];
                    const float b = acc[i][j + 2][r];
                    const float2 cs2 = tab[n * 32 + rsel + 16 * j];
                    dstb[(size_t)n * HD + rsel + 16 * j]      = f2bf((a * cs2.x - b * cs2.y) * qs);
                    dstb[(size_t)n * HD + rsel + 16 * j + 32] = f2bf((b * cs2.x + a * cs2.y) * qs);
                }
            }
    }
}

// ---------------------------------------------------------------------------
// MFMA flash attention — SWAPPED QK^T (T12 structural move): compute
// accS = mfma(K, Q) so each lane holds P[key=16n+4quad+r][q=16mi+rsel]
// for its OWN q-column. P then never touches LDS: exp -> RNE cvt -> pack
// into the PV A-fragment entirely in registers. Eliminates per-tile
// {16 ds_write + lgkm drain + 4 ds_read} AND the Pl buffer (17.4 KB) ->
// LDS 34.8 KB -> 3 blocks/CU (was 2). V's key->slot permutation (absorbed
// in gemm_qkv) makes the in-lane fragment order match PV's A-operand:
// ap[c] = [p(2c)[0..3], p(2c+1)[0..3]]. Operand-layout contract verified
// against the r8 working kernel (loads for aq/bk/bv unchanged).
// T1 XCD swizzle + T3 1-barrier dbuf staging retained. r9 lesson: (256,3)
// caps VGPR at ~170; demand here ~150 (r10 measured 120 for a bigger
// kernel) -> no spill expected; watch FETCH/WRITE for the spill signature.
// ---------------------------------------------------------------------------
__global__ __launch_bounds__(256, 3)
void flash_mfma(const ushort* __restrict__ Qb, const ushort* __restrict__ Kb,
                const ushort* __restrict__ Vp,
                float* __restrict__ Opart, float* __restrict__ lpart)
{
    __shared__ ushort Ks[2][64][68];   // [buf][key][d]
    __shared__ ushort Vs[2][64][68];   // [buf][d][slot]

    const int t    = threadIdx.x;
    const int lane = t & 63;
    const int wv   = t >> 6;
    const int rsel = lane & 15;
    const int quad = lane >> 4;

    // T1 XCD swizzle: 768 blocks; 32 q-tiles per (h,part) group, 24 groups.
    const int p  = blockIdx.x + 32 * (blockIdx.y + 12 * blockIdx.z);
    const int c  = p & 7;              // xcd slot
    const int r  = p >> 3;             // 0..95 position within xcd
    const int gi = r >> 5;             // 0..2  group index within xcd
    const int xq = r & 31;             // q-tile
    const int g  = gi * 8 + c;         // 0..23 (h,part) group
    const int h    = g % 12;
    const int part = g / 12;

    const int q0   = xq * 128 + wv * 32;
    const int Tbeg = (part * (SEQ / KSPLIT)) >> 6;
    const int Tend = Tbeg + (SEQ / KSPLIT) / 64;   // 32 tiles

    const int crow = t >> 2;           // 0..63 staging row
    const int ccol = (t & 3) * 16;     // 0/16/32/48 ushorts (2x16B per thread)

    // Q B-frags (persistent): lane holds Q[q=16mi+rsel][32ks + quad*8 ..]
    bf16x8 aq[2][2];
    #pragma unroll
    for (int mi = 0; mi < 2; ++mi)
        #pragma unroll
        for (int ks = 0; ks < 2; ++ks)
            aq[mi][ks] = *(const bf16x8*)&Qb[((size_t)h * SEQ + q0 + 16 * mi + rsel) * HD
                                             + ks * 32 + quad * 8];

    f32x4 accO[2][4] = {};
    float lsum[2] = {0.f, 0.f};

    // prologue: stage tile Tbeg into buf 0
    {
        const ushort* ksrc = &Kb[((size_t)h * SEQ + Tbeg * 64 + crow) * HD + ccol];
        const float4 k0 = *(const float4*)&ksrc[0];
        const float4 k1 = *(const float4*)&ksrc[8];
        const ushort* vsrc = &Vp[((size_t)h * HD + crow) * SEQ + Tbeg * 64 + ccol];
        const float4 v0 = *(const float4*)&vsrc[0];
        const float4 v1 = *(const float4*)&vsrc[8];
        *(float4*)&Ks[0][crow][ccol]     = k0;
        *(float4*)&Ks[0][crow][ccol + 8] = k1;
        *(float4*)&Vs[0][crow][ccol]     = v0;
        *(float4*)&Vs[0][crow][ccol + 8] = v1;
    }
    __syncthreads();

    int cur = 0;
    for (int T = Tbeg; T < Tend; ++T) {
        // issue next-tile K/V loads (clamped on last iter; L2-hot, harmless).
        const int Tn = (T + 1 < Tend) ? T + 1 : T;
        const ushort* ksrc = &Kb[((size_t)h * SEQ + Tn * 64 + crow) * HD + ccol];
        const float4 kn0 = *(const float4*)&ksrc[0];
        const float4 kn1 = *(const float4*)&ksrc[8];
        const ushort* vsrc = &Vp[((size_t)h * HD + crow) * SEQ + Tn * 64 + ccol];
        const float4 vn0 = *(const float4*)&vsrc[0];
        const float4 vn1 = *(const float4*)&vsrc[8];

        // K A-frags and V B-frags from LDS buf[cur]
        bf16x8 bk[4][2], bv[4][2];
        #pragma unroll
        for (int n = 0; n < 4; ++n)
            #pragma unroll
            for (int ks = 0; ks < 2; ++ks) {
                bk[n][ks] = *(const bf16x8*)&Ks[cur][16 * n + rsel][32 * ks + quad * 8];
                bv[n][ks] = *(const bf16x8*)&Vs[cur][16 * n + rsel][32 * ks + quad * 8];
            }

        #pragma unroll
        for (int mi = 0; mi < 2; ++mi) {
            // SWAPPED: accS[n] = K-block-n * Q^T -> lane holds
            // S[key=16n+4quad+r][q=16mi+rsel]
            f32x4 accS[4] = {};
            __builtin_amdgcn_s_setprio(1);
            #pragma unroll
            for (int ks = 0; ks < 2; ++ks)
                #pragma unroll
                for (int n = 0; n < 4; ++n)
                    accS[n] = __builtin_amdgcn_mfma_f32_16x16x32_bf16(
                        bk[n][ks], aq[mi][ks], accS[n], 0, 0, 0);
            __builtin_amdgcn_s_setprio(0);

            // P = 2^S, pack PV A-frags in-register:
            // ap[c] = [p(2c)[0..3], p(2c+1)[0..3]]  (V slot order matches)
            union { ushort u[8]; bf16x8 v; } ap0, ap1;
            float ls = 0.f;
            #pragma unroll
            for (int r = 0; r < 4; ++r) {
                const float p0 = __builtin_amdgcn_exp2f(accS[0][r]);
                const float p1 = __builtin_amdgcn_exp2f(accS[1][r]);
                const float p2 = __builtin_amdgcn_exp2f(accS[2][r]);
                const float p3 = __builtin_amdgcn_exp2f(accS[3][r]);
                ap0.u[r]     = f2bf_tw(p0);
                ap0.u[4 + r] = f2bf_tw(p1);
                ap1.u[r]     = f2bf_tw(p2);
                ap1.u[4 + r] = f2bf_tw(p3);
                ls += (p0 + p1) + (p2 + p3);
            }
            lsum[mi] += ls;

            __builtin_amdgcn_s_setprio(1);
            #pragma unroll
            for (int j = 0; j < 4; ++j) {
                accO[mi][j] = __builtin_amdgcn_mfma_f32_16x16x32_bf16(
                    ap0.v, bv[j][0], accO[mi][j], 0, 0, 0);
                accO[mi][j] = __builtin_amdgcn_mfma_f32_16x16x32_bf16(
                    ap1.v, bv[j][1], accO[mi][j], 0, 0, 0);
            }
            __builtin_amdgcn_s_setprio(0);
        }

        // write staged tile T+1 into buf[cur^1] (vmcnt wait lands here —
        // loads issued a full tile ago; cur^1 dead since prior barrier).
        *(float4*)&Ks[cur ^ 1][crow][ccol]     = kn0;
        *(float4*)&Ks[cur ^ 1][crow][ccol + 8] = kn1;
        *(float4*)&Vs[cur ^ 1][crow][ccol]     = vn0;
        *(float4*)&Vs[cur ^ 1][crow][ccol + 8] = vn1;
        __syncthreads();               // drains ds_writes, publishes buf[cur^1]
        cur ^= 1;
    }

    // l reduction across the 4 quads (lanes l, l^16, l^32, l^48 share q=rsel)
    #pragma unroll
    for (int mi = 0; mi < 2; ++mi) {
        float s = lsum[mi];
        s += __shfl_xor(s, 16);
        s += __shfl_xor(s, 32);
        lsum[mi] = s;
    }

    float* Ob = Opart + ((size_t)part * NHEADS + h) * SEQ * HD;
    float* lb = lpart + ((size_t)part * NHEADS + h) * SEQ;
    #pragma unroll
    for (int mi = 0; mi < 2; ++mi) {
        #pragma unroll
        for (int r = 0; r < 4; ++r) {
            const int n = q0 + 16 * mi + 4 * quad + r;
            #pragma unroll
            for (int j = 0; j < 4; ++j)
                Ob[(size_t)n * HD + 16 * j + rsel] = accO[mi][j][r];
        }
        if (quad == 0) lb[q0 + 16 * mi + rsel] = lsum[mi];
    }
}

// ---------------------------------------------------------------------------
// Split-K merge: AO[n][h*64+d] = (sum_p Opart) / (sum_p l), bf16.
// ---------------------------------------------------------------------------
__global__ __launch_bounds__(256)
void merge_k(const float* __restrict__ Opart, const float* __restrict__ lpart,
             ushort* __restrict__ AO)
{
    const int idx = blockIdx.x * 256 + threadIdx.x;
    const int dg = idx & 15;
    const int n  = (idx >> 4) & (SEQ - 1);
    const int h  = idx >> 16;

    float4 o = make_float4(0.f, 0.f, 0.f, 0.f);
    float l = 0.f;
    #pragma unroll
    for (int p = 0; p < KSPLIT; ++p) {
        const float4 v = *(const float4*)&Opart[(((size_t)p * NHEADS + h) * SEQ + n) * HD + dg * 4];
        o.x += v.x; o.y += v.y; o.z += v.z; o.w += v.w;
        l += lpart[((size_t)p * NHEADS + h) * SEQ + n];
    }
    const float inv = 1.f / l;
    ushort4 w;
    w.x = f2bf(o.x * inv); w.y = f2bf(o.y * inv);
    w.z = f2bf(o.z * inv); w.w = f2bf(o.w * inv);
    *(ushort4*)&AO[(size_t)n * DIM + h * HD + dg * 4] = w;
}

// ---------------------------------------------------------------------------
// Proj GEMM: out = attnout(bf16) @ proj_wb(bf16)^T + proj_b(f32), f32 out.
// T3 1-barrier double-buffered K-loop (same as gemm_qkv).
// ---------------------------------------------------------------------------
__global__ __launch_bounds__(256)
void gemm_proj(const ushort* __restrict__ A, const ushort* __restrict__ B,
               const float* __restrict__ bias, float* __restrict__ out)
{
    constexpr int BM = 128, BN = 128, BK = 64;
    __shared__ __attribute__((aligned(16))) ushort As[2][BM][BK];
    __shared__ __attribute__((aligned(16))) ushort Bs[2][BN][BK];

    const int t    = threadIdx.x;
    const int lane = t & 63;
    const int wv   = t >> 6;
    const int wm   = (wv >> 1) * 64;
    const int wn   = (wv & 1) * 64;
    const int m0   = blockIdx.y * BM;
    const int n0   = blockIdx.x * BN;

    f32x4 acc[4][4] = {};

    const int lrow = lane >> 3;
    const int lch  = (lane & 7) * 8;

    #pragma unroll
    for (int i = 0; i < 4; ++i) {
        const int rb = i * 32 + wv * 8;
        gload16(&A[(size_t)(m0 + rb + lrow) * DIM + lch], &As[0][rb][0]);
        gload16(&B[(size_t)(n0 + rb + lrow) * DIM + lch], &Bs[0][rb][0]);
    }
    __syncthreads();

    int cur = 0;
    for (int k0 = 0; k0 < DIM; k0 += BK) {
        if (k0 + BK < DIM) {
            #pragma unroll
            for (int i = 0; i < 4; ++i) {
                const int rb = i * 32 + wv * 8;
                gload16(&A[(size_t)(m0 + rb + lrow) * DIM + k0 + BK + lch],
                        &As[cur ^ 1][rb][0]);
                gload16(&B[(size_t)(n0 + rb + lrow) * DIM + k0 + BK + lch],
                        &Bs[cur ^ 1][rb][0]);
            }
        }

        #pragma unroll
        for (int ks = 0; ks < BK; ks += 32) {
            const int koff = ks + ((lane >> 4) << 3);
            const int rs = lane & 15;
            bf16x8 af[4], bf[4];
            #pragma unroll
            for (int i = 0; i < 4; ++i) {
                af[i] = *(const bf16x8*)&As[cur][wm + i * 16 + rs][koff];
                bf[i] = *(const bf16x8*)&Bs[cur][wn + i * 16 + rs][koff];
            }
            #pragma unroll
            for (int i = 0; i < 4; ++i)
                #pragma unroll
                for (int j = 0; j < 4; ++j)
                    acc[i][j] = __builtin_amdgcn_mfma_f32_16x16x32_bf16(
                        af[i], bf[j], acc[i][j], 0, 0, 0);
        }
        __syncthreads();
        cur ^= 1;
    }

    const int rbase = m0 + wm + ((lane >> 4) << 2);
    const int cbase = n0 + wn + (lane & 15);

    #pragma unroll
    for (int j = 0; j < 4; ++j) {
        const int col = cbase + j * 16;
        const float bv = bias[col];
        #pragma unroll
        for (int i = 0; i < 4; ++i) {
            const int row0 = rbase + i * 16;
            #pragma unroll
            for (int r = 0; r < 4; ++r)
                out[(size_t)(row0 + r) * DIM + col] = acc[i][j][r] + bv;
        }
    }
}

// ---------------------------------------------------------------------------
extern "C" void kernel_launch(void* const* d_in, const int* in_sizes, int n_in,
                              void* d_out, int out_size, void* d_ws, size_t ws_size,
                              hipStream_t stream)
{
    const float* x      = (const float*)d_in[0];
    const float* qkv_w  = (const float*)d_in[1];
    const float* proj_w = (const float*)d_in[2];
    const float* proj_b = (const float*)d_in[3];

    const size_t headsz = (size_t)NHEADS * SEQ * HD;       // 3,145,728
    char* p = (char*)d_ws;
    ushort* Qb    = (ushort*)p;                 p += headsz * 2;
    ushort* Kb    = (ushort*)p;                 p += headsz * 2;
    ushort* Vp    = (ushort*)p;                 p += headsz * 2;
    ushort* AO    = (ushort*)p;                 p += (size_t)SEQ * DIM * 2;
    float*  Opart = (float*)p;                  p += (size_t)KSPLIT * headsz * 4;
    float*  lpart = (float*)p;                  p += (size_t)KSPLIT * NHEADS * SEQ * 4;
    float2* tab   = (float2*)p;                 p += (size_t)SEQ * 32 * sizeof(float2);
    ushort* xb    = (ushort*)p;                 p += (size_t)SEQ * DIM * 2;
    ushort* qwb   = (ushort*)p;                 p += (size_t)3 * DIM * DIM * 2;
    ushort* pwb   = (ushort*)p;
    float*  out   = (float*)d_out;

    prep<<<5888, 256, 0, stream>>>(x, qkv_w, proj_w, xb, qwb, pwb, tab);

    gemm_qkv<<<dim3(3 * DIM / 128, SEQ / 128), 256, 0, stream>>>(
        xb, qwb, tab, Qb, Kb, Vp);

    flash_mfma<<<dim3(SEQ / 128, NHEADS, KSPLIT), 256, 0, stream>>>(
        Qb, Kb, Vp, Opart, lpart);

    merge_k<<<(NHEADS * SEQ * 16) / 256, 256, 0, stream>>>(Opart, lpart, AO);

    gemm_proj<<<dim3(DIM / 128, SEQ / 128), 256, 0, stream>>>(
        AO, pwb, proj_b, out);
}

// Round 12
// 214.678 us; speedup vs baseline: 1.1076x; 1.1076x over previous
//
#include <hip/hip_runtime.h>
#include <hip/hip_bf16.h>
#include <math.h>

#define DIM 768
#define NHEADS 12
#define HD 64
#define SEQ 4096
#define KSPLIT 2

typedef __bf16 bf16x8 __attribute__((ext_vector_type(8)));
typedef float f32x4 __attribute__((ext_vector_type(4)));
typedef uint  u32x4 __attribute__((ext_vector_type(4)));

// Native bf16 convert (RNE) — used outside flash.
__device__ inline ushort f2bf(float f) {
    __bf16 b = (__bf16)f;
    union { __bf16 b; ushort u; } v; v.b = b;
    return v.u;
}

// Manual RNE twiddle — used inside flash (unbiased RNE REQUIRED:
// v_cvt_pk_bf16_f32 biased P downward, failed absmax 4.3e-2 in round 1).
__device__ inline ushort f2bf_tw(float f) {
    union { float f; uint u; } v; v.f = f;
    uint r = v.u + 0x7FFF + ((v.u >> 16) & 1);
    return (ushort)(r >> 16);
}

// global -> LDS direct copy, 16B per lane. LDS dest is WAVE-UNIFORM base
// (hw adds lane*16); global src is per-lane.
__device__ inline void gload16(const ushort* gsrc, ushort* lbase) {
    __builtin_amdgcn_global_load_lds(
        (const __attribute__((address_space(1))) uint*)gsrc,
        (__attribute__((address_space(3))) uint*)lbase, 16, 0, 0);
}

// ---------------------------------------------------------------------------
// Fused prologue: block-range dispatch over
//   [0,3072)    : x f32 -> bf16            (4096*768 /4 /256)
//   [3072,4800) : qkv_w f32 -> bf16        (3*768*768 /4 /256)
//   [4800,5376) : proj_w f32 -> bf16       (768*768 /4 /256)
//   [5376,5888) : RoPE table tab[n][j]     (4096*32 /256)
// ---------------------------------------------------------------------------
__global__ __launch_bounds__(256)
void prep(const float* __restrict__ x, const float* __restrict__ qkv_w,
          const float* __restrict__ proj_w,
          ushort* __restrict__ xb, ushort* __restrict__ qwb,
          ushort* __restrict__ pwb, float2* __restrict__ tab)
{
    const int b = blockIdx.x;
    if (b < 5376) {
        const float* src; ushort* dst; int i;
        if (b < 3072)      { src = x;      dst = xb;  i = b * 256 + threadIdx.x; }
        else if (b < 4800) { src = qkv_w;  dst = qwb; i = (b - 3072) * 256 + threadIdx.x; }
        else               { src = proj_w; dst = pwb; i = (b - 4800) * 256 + threadIdx.x; }
        const float4 v = ((const float4*)src)[i];
        ushort4 w;
        w.x = f2bf(v.x); w.y = f2bf(v.y); w.z = f2bf(v.z); w.w = f2bf(v.w);
        ((ushort4*)dst)[i] = w;
    } else {
        const int idx = (b - 5376) * 256 + threadIdx.x;   // 4096*32
        const int j = idx & 31;
        const int n = idx >> 5;
        const float invf = (float)pow(10000.0, -(double)j / 32.0);
        const float ang  = (float)n * invf;               // f32 (matches ref freqs)
        double s, c;
        sincos((double)ang, &s, &c);
        tab[idx] = make_float2((float)c, (float)s);
    }
}

// ---------------------------------------------------------------------------
// QKV GEMM (bf16 in) + fused RoPE + layout. T3 1-barrier double-buffered
// K-loop. LDS 64 KB -> 2 blocks/CU.
//   t=0 (q): RoPE, *0.125*log2e (exp->exp2 fold), bf16 -> Qb[h][n][d]
//   t=1 (k): RoPE, bf16 -> Kb[h][n][d]
//   t=2 (v): bf16 -> Vp[h][d][64T + slot], slot permuted for the SWAPPED-
//            QK^T flash PV path: key kappa=16i+4quad+r -> slot
//            32*(i>>1) + 8*quad + 4*(i&1) + r  (so flash's in-register P
//            fragments [p(n=2c)[0..3], p(2c+1)[0..3]] multiply V directly).
// ---------------------------------------------------------------------------
__global__ __launch_bounds__(256)
void gemm_qkv(const ushort* __restrict__ A, const ushort* __restrict__ B,
              const float2* __restrict__ tab,
              ushort* __restrict__ Qb, ushort* __restrict__ Kb,
              ushort* __restrict__ Vp)
{
    constexpr int BM = 128, BN = 128, BK = 64;
    __shared__ __attribute__((aligned(16))) ushort Ah[2][BM][BK];
    __shared__ __attribute__((aligned(16))) ushort Bh[2][BN][BK];

    const int t    = threadIdx.x;
    const int lane = t & 63;
    const int wv   = t >> 6;
    const int wm   = (wv >> 1) * 64;
    const int wn   = (wv & 1) * 64;
    const int m0   = blockIdx.y * BM;
    const int n0   = blockIdx.x * BN;

    f32x4 acc[4][4] = {};

    const int lrow = lane >> 3;        // 0..7  row within 8-row wave stripe
    const int lch  = (lane & 7) * 8;   // 16B chunk (ushort offset)

    // prologue: stage k0=0 into buf 0
    #pragma unroll
    for (int i = 0; i < 4; ++i) {
        const int rb = i * 32 + wv * 8;          // wave-uniform row base
        gload16(&A[(size_t)(m0 + rb + lrow) * DIM + lch], &Ah[0][rb][0]);
        gload16(&B[(size_t)(n0 + rb + lrow) * DIM + lch], &Bh[0][rb][0]);
    }
    __syncthreads();

    int cur = 0;
    for (int k0 = 0; k0 < DIM; k0 += BK) {
        if (k0 + BK < DIM) {       // prefetch next K-tile into buf^1
            #pragma unroll
            for (int i = 0; i < 4; ++i) {
                const int rb = i * 32 + wv * 8;
                gload16(&A[(size_t)(m0 + rb + lrow) * DIM + k0 + BK + lch],
                        &Ah[cur ^ 1][rb][0]);
                gload16(&B[(size_t)(n0 + rb + lrow) * DIM + k0 + BK + lch],
                        &Bh[cur ^ 1][rb][0]);
            }
        }

        #pragma unroll
        for (int ks = 0; ks < BK; ks += 32) {
            const int koff = ks + ((lane >> 4) << 3);
            const int rs = lane & 15;
            bf16x8 af[4], bf[4];
            #pragma unroll
            for (int i = 0; i < 4; ++i) {
                af[i] = *(const bf16x8*)&Ah[cur][wm + i * 16 + rs][koff];
                bf[i] = *(const bf16x8*)&Bh[cur][wn + i * 16 + rs][koff];
            }
            #pragma unroll
            for (int i = 0; i < 4; ++i)
                #pragma unroll
                for (int j = 0; j < 4; ++j)
                    acc[i][j] = __builtin_amdgcn_mfma_f32_16x16x32_bf16(
                        af[i], bf[j], acc[i][j], 0, 0, 0);
        }
        __syncthreads();   // drains vmcnt (prefetch landed, hidden) + lgkm;
        cur ^= 1;          // all waves done reading old buf
    }

    const int rsel  = lane & 15;
    const int quad  = lane >> 4;
    const int rbase = m0 + wm + (quad << 2);
    const int c0    = n0 + wn;          // 64-aligned -> one (t,h) per wave
    const int tt    = c0 / DIM;
    const int h     = (c0 % DIM) >> 6;

    if (tt == 2) {
        // key kappa (within 64-tile) = 16i + 4quad + r
        // -> slot 32*(i>>1) + 8*quad + 4*(i&1) + r   (swapped-PV order)
        const int T = (m0 + wm) >> 6;
        #pragma unroll
        for (int j = 0; j < 4; ++j) {
            const int d = rsel + 16 * j;
            ushort vvA[8], vvB[8];
            #pragma unroll
            for (int i2 = 0; i2 < 2; ++i2)
                #pragma unroll
                for (int r = 0; r < 4; ++r) {
                    vvA[4 * i2 + r] = f2bf(acc[i2][j][r]);        // i=0,1 -> c=0
                    vvB[4 * i2 + r] = f2bf(acc[2 + i2][j][r]);    // i=2,3 -> c=1
                }
            ushort* dst = &Vp[((size_t)h * HD + d) * SEQ + T * 64];
            *(float4*)&dst[8 * quad]      = *(const float4*)&vvA[0];
            *(float4*)&dst[32 + 8 * quad] = *(const float4*)&vvB[0];
        }
    } else {
        ushort* dstb = (tt == 0 ? Qb : Kb) + (size_t)h * SEQ * HD;
        // 0.125 * log2(e): flash computes exp(S) via v_exp_f32 (2^S').
        const float qs = (tt == 0) ? 0.18033688011112042f : 1.0f;
        #pragma unroll
        for (int i = 0; i < 4; ++i)
            #pragma unroll
            for (int r = 0; r < 4; ++r) {
                const int n = rbase + i * 16 + r;
                #pragma unroll
                for (int j = 0; j < 2; ++j) {
                    const float a = acc[i][j][r];
                    const float b = acc[i][j + 2][r];
                    const float2 cs2 = tab[n * 32 + rsel + 16 * j];
                    dstb[(size_t)n * HD + rsel + 16 * j]      = f2bf((a * cs2.x - b * cs2.y) * qs);
                    dstb[(size_t)n * HD + rsel + 16 * j + 32] = f2bf((b * cs2.x + a * cs2.y) * qs);
                }
            }
    }
}

// ---------------------------------------------------------------------------
// MFMA flash attention — SWAPPED QK^T with REGISTER-ONLY P packing.
// r11's union{ushort[8];bf16x8} forced a scratch alloca (WRITE 25->63 MB,
// flash 120us). Fix: named scalar uints (tw(lo) | tw(hi)<<16) assembled
// into a u32x4 vector literal and bit_cast to bf16x8 — pure insertelement,
// nothing addressable, nothing to spill.
// Structure (verified r11, refcheck passed): accS = mfma(K, Q) -> lane
// holds P[key=16n+4quad+r][q=16mi+rsel]; exp -> RNE -> pack -> PV all in
// registers; V's key->slot permutation absorbed in gemm_qkv. No Pl buffer:
// LDS 34.8 KB -> 3 blocks/CU. T1 XCD swizzle + T3 1-barrier dbuf retained.
// ---------------------------------------------------------------------------
__global__ __launch_bounds__(256, 3)
void flash_mfma(const ushort* __restrict__ Qb, const ushort* __restrict__ Kb,
                const ushort* __restrict__ Vp,
                float* __restrict__ Opart, float* __restrict__ lpart)
{
    __shared__ ushort Ks[2][64][68];   // [buf][key][d]
    __shared__ ushort Vs[2][64][68];   // [buf][d][slot]

    const int t    = threadIdx.x;
    const int lane = t & 63;
    const int wv   = t >> 6;
    const int rsel = lane & 15;
    const int quad = lane >> 4;

    // T1 XCD swizzle: 768 blocks; 32 q-tiles per (h,part) group, 24 groups.
    const int p  = blockIdx.x + 32 * (blockIdx.y + 12 * blockIdx.z);
    const int c  = p & 7;              // xcd slot
    const int r  = p >> 3;             // 0..95 position within xcd
    const int gi = r >> 5;             // 0..2  group index within xcd
    const int xq = r & 31;             // q-tile
    const int g  = gi * 8 + c;         // 0..23 (h,part) group
    const int h    = g % 12;
    const int part = g / 12;

    const int q0   = xq * 128 + wv * 32;
    const int Tbeg = (part * (SEQ / KSPLIT)) >> 6;
    const int Tend = Tbeg + (SEQ / KSPLIT) / 64;   // 32 tiles

    const int crow = t >> 2;           // 0..63 staging row
    const int ccol = (t & 3) * 16;     // 0/16/32/48 ushorts (2x16B per thread)

    // Q B-frags (persistent): lane holds Q[q=16mi+rsel][32ks + quad*8 ..]
    bf16x8 aq[2][2];
    #pragma unroll
    for (int mi = 0; mi < 2; ++mi)
        #pragma unroll
        for (int ks = 0; ks < 2; ++ks)
            aq[mi][ks] = *(const bf16x8*)&Qb[((size_t)h * SEQ + q0 + 16 * mi + rsel) * HD
                                             + ks * 32 + quad * 8];

    f32x4 accO[2][4] = {};
    float lsum[2] = {0.f, 0.f};

    // prologue: stage tile Tbeg into buf 0
    {
        const ushort* ksrc = &Kb[((size_t)h * SEQ + Tbeg * 64 + crow) * HD + ccol];
        const float4 k0 = *(const float4*)&ksrc[0];
        const float4 k1 = *(const float4*)&ksrc[8];
        const ushort* vsrc = &Vp[((size_t)h * HD + crow) * SEQ + Tbeg * 64 + ccol];
        const float4 v0 = *(const float4*)&vsrc[0];
        const float4 v1 = *(const float4*)&vsrc[8];
        *(float4*)&Ks[0][crow][ccol]     = k0;
        *(float4*)&Ks[0][crow][ccol + 8] = k1;
        *(float4*)&Vs[0][crow][ccol]     = v0;
        *(float4*)&Vs[0][crow][ccol + 8] = v1;
    }
    __syncthreads();

    int cur = 0;
    for (int T = Tbeg; T < Tend; ++T) {
        // issue next-tile K/V loads (clamped on last iter; L2-hot, harmless).
        const int Tn = (T + 1 < Tend) ? T + 1 : T;
        const ushort* ksrc = &Kb[((size_t)h * SEQ + Tn * 64 + crow) * HD + ccol];
        const float4 kn0 = *(const float4*)&ksrc[0];
        const float4 kn1 = *(const float4*)&ksrc[8];
        const ushort* vsrc = &Vp[((size_t)h * HD + crow) * SEQ + Tn * 64 + ccol];
        const float4 vn0 = *(const float4*)&vsrc[0];
        const float4 vn1 = *(const float4*)&vsrc[8];

        // K A-frags and V B-frags from LDS buf[cur]
        bf16x8 bk[4][2], bv[4][2];
        #pragma unroll
        for (int n = 0; n < 4; ++n)
            #pragma unroll
            for (int ks = 0; ks < 2; ++ks) {
                bk[n][ks] = *(const bf16x8*)&Ks[cur][16 * n + rsel][32 * ks + quad * 8];
                bv[n][ks] = *(const bf16x8*)&Vs[cur][16 * n + rsel][32 * ks + quad * 8];
            }

        #pragma unroll
        for (int mi = 0; mi < 2; ++mi) {
            // SWAPPED: accS[n] = K-block-n * Q^T -> lane holds
            // S[key=16n+4quad+r][q=16mi+rsel]
            f32x4 accS[4] = {};
            __builtin_amdgcn_s_setprio(1);
            #pragma unroll
            for (int ks = 0; ks < 2; ++ks)
                #pragma unroll
                for (int n = 0; n < 4; ++n)
                    accS[n] = __builtin_amdgcn_mfma_f32_16x16x32_bf16(
                        bk[n][ks], aq[mi][ks], accS[n], 0, 0, 0);
            __builtin_amdgcn_s_setprio(0);

            // P = 2^S; pack PV A-frags ENTIRELY in registers via named
            // scalars -> u32x4 literal -> bit_cast (no alloca, no scratch).
            const float p00 = __builtin_amdgcn_exp2f(accS[0][0]);
            const float p01 = __builtin_amdgcn_exp2f(accS[0][1]);
            const float p02 = __builtin_amdgcn_exp2f(accS[0][2]);
            const float p03 = __builtin_amdgcn_exp2f(accS[0][3]);
            const float p10 = __builtin_amdgcn_exp2f(accS[1][0]);
            const float p11 = __builtin_amdgcn_exp2f(accS[1][1]);
            const float p12 = __builtin_amdgcn_exp2f(accS[1][2]);
            const float p13 = __builtin_amdgcn_exp2f(accS[1][3]);
            const float p20 = __builtin_amdgcn_exp2f(accS[2][0]);
            const float p21 = __builtin_amdgcn_exp2f(accS[2][1]);
            const float p22 = __builtin_amdgcn_exp2f(accS[2][2]);
            const float p23 = __builtin_amdgcn_exp2f(accS[2][3]);
            const float p30 = __builtin_amdgcn_exp2f(accS[3][0]);
            const float p31 = __builtin_amdgcn_exp2f(accS[3][1]);
            const float p32 = __builtin_amdgcn_exp2f(accS[3][2]);
            const float p33 = __builtin_amdgcn_exp2f(accS[3][3]);

            const u32x4 aw0 = {
                (uint)f2bf_tw(p00) | ((uint)f2bf_tw(p01) << 16),
                (uint)f2bf_tw(p02) | ((uint)f2bf_tw(p03) << 16),
                (uint)f2bf_tw(p10) | ((uint)f2bf_tw(p11) << 16),
                (uint)f2bf_tw(p12) | ((uint)f2bf_tw(p13) << 16) };
            const u32x4 aw1 = {
                (uint)f2bf_tw(p20) | ((uint)f2bf_tw(p21) << 16),
                (uint)f2bf_tw(p22) | ((uint)f2bf_tw(p23) << 16),
                (uint)f2bf_tw(p30) | ((uint)f2bf_tw(p31) << 16),
                (uint)f2bf_tw(p32) | ((uint)f2bf_tw(p33) << 16) };
            const bf16x8 ap0 = __builtin_bit_cast(bf16x8, aw0);
            const bf16x8 ap1 = __builtin_bit_cast(bf16x8, aw1);

            lsum[mi] += ((p00 + p01) + (p02 + p03)) + ((p10 + p11) + (p12 + p13))
                      + ((p20 + p21) + (p22 + p23)) + ((p30 + p31) + (p32 + p33));

            __builtin_amdgcn_s_setprio(1);
            #pragma unroll
            for (int j = 0; j < 4; ++j) {
                accO[mi][j] = __builtin_amdgcn_mfma_f32_16x16x32_bf16(
                    ap0, bv[j][0], accO[mi][j], 0, 0, 0);
                accO[mi][j] = __builtin_amdgcn_mfma_f32_16x16x32_bf16(
                    ap1, bv[j][1], accO[mi][j], 0, 0, 0);
            }
            __builtin_amdgcn_s_setprio(0);
        }

        // write staged tile T+1 into buf[cur^1] (vmcnt wait lands here —
        // loads issued a full tile ago; cur^1 dead since prior barrier).
        *(float4*)&Ks[cur ^ 1][crow][ccol]     = kn0;
        *(float4*)&Ks[cur ^ 1][crow][ccol + 8] = kn1;
        *(float4*)&Vs[cur ^ 1][crow][ccol]     = vn0;
        *(float4*)&Vs[cur ^ 1][crow][ccol + 8] = vn1;
        __syncthreads();               // drains ds_writes, publishes buf[cur^1]
        cur ^= 1;
    }

    // l reduction across the 4 quads (lanes l, l^16, l^32, l^48 share q=rsel)
    #pragma unroll
    for (int mi = 0; mi < 2; ++mi) {
        float s = lsum[mi];
        s += __shfl_xor(s, 16);
        s += __shfl_xor(s, 32);
        lsum[mi] = s;
    }

    float* Ob = Opart + ((size_t)part * NHEADS + h) * SEQ * HD;
    float* lb = lpart + ((size_t)part * NHEADS + h) * SEQ;
    #pragma unroll
    for (int mi = 0; mi < 2; ++mi) {
        #pragma unroll
        for (int r = 0; r < 4; ++r) {
            const int n = q0 + 16 * mi + 4 * quad + r;
            #pragma unroll
            for (int j = 0; j < 4; ++j)
                Ob[(size_t)n * HD + 16 * j + rsel] = accO[mi][j][r];
        }
        if (quad == 0) lb[q0 + 16 * mi + rsel] = lsum[mi];
    }
}

// ---------------------------------------------------------------------------
// Split-K merge: AO[n][h*64+d] = (sum_p Opart) / (sum_p l), bf16.
// ---------------------------------------------------------------------------
__global__ __launch_bounds__(256)
void merge_k(const float* __restrict__ Opart, const float* __restrict__ lpart,
             ushort* __restrict__ AO)
{
    const int idx = blockIdx.x * 256 + threadIdx.x;
    const int dg = idx & 15;
    const int n  = (idx >> 4) & (SEQ - 1);
    const int h  = idx >> 16;

    float4 o = make_float4(0.f, 0.f, 0.f, 0.f);
    float l = 0.f;
    #pragma unroll
    for (int p = 0; p < KSPLIT; ++p) {
        const float4 v = *(const float4*)&Opart[(((size_t)p * NHEADS + h) * SEQ + n) * HD + dg * 4];
        o.x += v.x; o.y += v.y; o.z += v.z; o.w += v.w;
        l += lpart[((size_t)p * NHEADS + h) * SEQ + n];
    }
    const float inv = 1.f / l;
    ushort4 w;
    w.x = f2bf(o.x * inv); w.y = f2bf(o.y * inv);
    w.z = f2bf(o.z * inv); w.w = f2bf(o.w * inv);
    *(ushort4*)&AO[(size_t)n * DIM + h * HD + dg * 4] = w;
}

// ---------------------------------------------------------------------------
// Proj GEMM: out = attnout(bf16) @ proj_wb(bf16)^T + proj_b(f32), f32 out.
// T3 1-barrier double-buffered K-loop (same as gemm_qkv).
// ---------------------------------------------------------------------------
__global__ __launch_bounds__(256)
void gemm_proj(const ushort* __restrict__ A, const ushort* __restrict__ B,
               const float* __restrict__ bias, float* __restrict__ out)
{
    constexpr int BM = 128, BN = 128, BK = 64;
    __shared__ __attribute__((aligned(16))) ushort As[2][BM][BK];
    __shared__ __attribute__((aligned(16))) ushort Bs[2][BN][BK];

    const int t    = threadIdx.x;
    const int lane = t & 63;
    const int wv   = t >> 6;
    const int wm   = (wv >> 1) * 64;
    const int wn   = (wv & 1) * 64;
    const int m0   = blockIdx.y * BM;
    const int n0   = blockIdx.x * BN;

    f32x4 acc[4][4] = {};

    const int lrow = lane >> 3;
    const int lch  = (lane & 7) * 8;

    #pragma unroll
    for (int i = 0; i < 4; ++i) {
        const int rb = i * 32 + wv * 8;
        gload16(&A[(size_t)(m0 + rb + lrow) * DIM + lch], &As[0][rb][0]);
        gload16(&B[(size_t)(n0 + rb + lrow) * DIM + lch], &Bs[0][rb][0]);
    }
    __syncthreads();

    int cur = 0;
    for (int k0 = 0; k0 < DIM; k0 += BK) {
        if (k0 + BK < DIM) {
            #pragma unroll
            for (int i = 0; i < 4; ++i) {
                const int rb = i * 32 + wv * 8;
                gload16(&A[(size_t)(m0 + rb + lrow) * DIM + k0 + BK + lch],
                        &As[cur ^ 1][rb][0]);
                gload16(&B[(size_t)(n0 + rb + lrow) * DIM + k0 + BK + lch],
                        &Bs[cur ^ 1][rb][0]);
            }
        }

        #pragma unroll
        for (int ks = 0; ks < BK; ks += 32) {
            const int koff = ks + ((lane >> 4) << 3);
            const int rs = lane & 15;
            bf16x8 af[4], bf[4];
            #pragma unroll
            for (int i = 0; i < 4; ++i) {
                af[i] = *(const bf16x8*)&As[cur][wm + i * 16 + rs][koff];
                bf[i] = *(const bf16x8*)&Bs[cur][wn + i * 16 + rs][koff];
            }
            #pragma unroll
            for (int i = 0; i < 4; ++i)
                #pragma unroll
                for (int j = 0; j < 4; ++j)
                    acc[i][j] = __builtin_amdgcn_mfma_f32_16x16x32_bf16(
                        af[i], bf[j], acc[i][j], 0, 0, 0);
        }
        __syncthreads();
        cur ^= 1;
    }

    const int rbase = m0 + wm + ((lane >> 4) << 2);
    const int cbase = n0 + wn + (lane & 15);

    #pragma unroll
    for (int j = 0; j < 4; ++j) {
        const int col = cbase + j * 16;
        const float bv = bias[col];
        #pragma unroll
        for (int i = 0; i < 4; ++i) {
            const int row0 = rbase + i * 16;
            #pragma unroll
            for (int r = 0; r < 4; ++r)
                out[(size_t)(row0 + r) * DIM + col] = acc[i][j][r] + bv;
        }
    }
}

// ---------------------------------------------------------------------------
extern "C" void kernel_launch(void* const* d_in, const int* in_sizes, int n_in,
                              void* d_out, int out_size, void* d_ws, size_t ws_size,
                              hipStream_t stream)
{
    const float* x      = (const float*)d_in[0];
    const float* qkv_w  = (const float*)d_in[1];
    const float* proj_w = (const float*)d_in[2];
    const float* proj_b = (const float*)d_in[3];

    const size_t headsz = (size_t)NHEADS * SEQ * HD;       // 3,145,728
    char* p = (char*)d_ws;
    ushort* Qb    = (ushort*)p;                 p += headsz * 2;
    ushort* Kb    = (ushort*)p;                 p += headsz * 2;
    ushort* Vp    = (ushort*)p;                 p += headsz * 2;
    ushort* AO    = (ushort*)p;                 p += (size_t)SEQ * DIM * 2;
    float*  Opart = (float*)p;                  p += (size_t)KSPLIT * headsz * 4;
    float*  lpart = (float*)p;                  p += (size_t)KSPLIT * NHEADS * SEQ * 4;
    float2* tab   = (float2*)p;                 p += (size_t)SEQ * 32 * sizeof(float2);
    ushort* xb    = (ushort*)p;                 p += (size_t)SEQ * DIM * 2;
    ushort* qwb   = (ushort*)p;                 p += (size_t)3 * DIM * DIM * 2;
    ushort* pwb   = (ushort*)p;
    float*  out   = (float*)d_out;

    prep<<<5888, 256, 0, stream>>>(x, qkv_w, proj_w, xb, qwb, pwb, tab);

    gemm_qkv<<<dim3(3 * DIM / 128, SEQ / 128), 256, 0, stream>>>(
        xb, qwb, tab, Qb, Kb, Vp);

    flash_mfma<<<dim3(SEQ / 128, NHEADS, KSPLIT), 256, 0, stream>>>(
        Qb, Kb, Vp, Opart, lpart);

    merge_k<<<(NHEADS * SEQ * 16) / 256, 256, 0, stream>>>(Opart, lpart, AO);

    gemm_proj<<<dim3(DIM / 128, SEQ / 128), 256, 0, stream>>>(
        AO, pwb, proj_b, out);
}

// Round 13
// 205.674 us; speedup vs baseline: 1.1561x; 1.0438x over previous
//
#include <hip/hip_runtime.h>
#include <hip/hip_bf16.h>
#include <math.h>

#define DIM 768
#define NHEADS 12
#define HD 64
#define SEQ 4096
#define KSPLIT 2

typedef __bf16 bf16x8 __attribute__((ext_vector_type(8)));
typedef float f32x4 __attribute__((ext_vector_type(4)));
typedef uint  u32x4 __attribute__((ext_vector_type(4)));

// Native bf16 convert (RNE) — used outside flash.
__device__ inline ushort f2bf(float f) {
    __bf16 b = (__bf16)f;
    union { __bf16 b; ushort u; } v; v.b = b;
    return v.u;
}

// Manual RNE twiddle — used inside flash (unbiased RNE REQUIRED:
// v_cvt_pk_bf16_f32 biased P downward, failed absmax 4.3e-2 in round 1).
__device__ inline ushort f2bf_tw(float f) {
    union { float f; uint u; } v; v.f = f;
    uint r = v.u + 0x7FFF + ((v.u >> 16) & 1);
    return (ushort)(r >> 16);
}

// global -> LDS direct copy, 16B per lane. LDS dest is WAVE-UNIFORM base
// (hw adds lane*16); global src is per-lane.
__device__ inline void gload16(const ushort* gsrc, ushort* lbase) {
    __builtin_amdgcn_global_load_lds(
        (const __attribute__((address_space(1))) uint*)gsrc,
        (__attribute__((address_space(3))) uint*)lbase, 16, 0, 0);
}

// ---------------------------------------------------------------------------
// Fused prologue: block-range dispatch over
//   [0,3072)    : x f32 -> bf16            (4096*768 /4 /256)
//   [3072,4800) : qkv_w f32 -> bf16        (3*768*768 /4 /256)
//   [4800,5376) : proj_w f32 -> bf16       (768*768 /4 /256)
//   [5376,5888) : RoPE table tab[n][j]     (4096*32 /256)
// ---------------------------------------------------------------------------
__global__ __launch_bounds__(256)
void prep(const float* __restrict__ x, const float* __restrict__ qkv_w,
          const float* __restrict__ proj_w,
          ushort* __restrict__ xb, ushort* __restrict__ qwb,
          ushort* __restrict__ pwb, float2* __restrict__ tab)
{
    const int b = blockIdx.x;
    if (b < 5376) {
        const float* src; ushort* dst; int i;
        if (b < 3072)      { src = x;      dst = xb;  i = b * 256 + threadIdx.x; }
        else if (b < 4800) { src = qkv_w;  dst = qwb; i = (b - 3072) * 256 + threadIdx.x; }
        else               { src = proj_w; dst = pwb; i = (b - 4800) * 256 + threadIdx.x; }
        const float4 v = ((const float4*)src)[i];
        ushort4 w;
        w.x = f2bf(v.x); w.y = f2bf(v.y); w.z = f2bf(v.z); w.w = f2bf(v.w);
        ((ushort4*)dst)[i] = w;
    } else {
        const int idx = (b - 5376) * 256 + threadIdx.x;   // 4096*32
        const int j = idx & 31;
        const int n = idx >> 5;
        const float invf = (float)pow(10000.0, -(double)j / 32.0);
        const float ang  = (float)n * invf;               // f32 (matches ref freqs)
        double s, c;
        sincos((double)ang, &s, &c);
        tab[idx] = make_float2((float)c, (float)s);
    }
}

// ---------------------------------------------------------------------------
// QKV GEMM (bf16 in) + fused RoPE + layout. T3 1-barrier double-buffered
// K-loop. LDS 64 KB -> 2 blocks/CU.
//   t=0 (q): RoPE, *0.125*log2e (exp->exp2 fold), bf16 -> Qb[h][n][d]
//   t=1 (k): RoPE, bf16 -> Kb[h][n][d]
//   t=2 (v): bf16 -> Vp[h][d][64T + slot], slot permuted for the SWAPPED-
//            QK^T flash PV path: key kappa=16i+4quad+r -> slot
//            32*(i>>1) + 8*quad + 4*(i&1) + r  (so flash's in-register P
//            fragments [p(n=2c)[0..3], p(2c+1)[0..3]] multiply V directly).
// ---------------------------------------------------------------------------
__global__ __launch_bounds__(256)
void gemm_qkv(const ushort* __restrict__ A, const ushort* __restrict__ B,
              const float2* __restrict__ tab,
              ushort* __restrict__ Qb, ushort* __restrict__ Kb,
              ushort* __restrict__ Vp)
{
    constexpr int BM = 128, BN = 128, BK = 64;
    __shared__ __attribute__((aligned(16))) ushort Ah[2][BM][BK];
    __shared__ __attribute__((aligned(16))) ushort Bh[2][BN][BK];

    const int t    = threadIdx.x;
    const int lane = t & 63;
    const int wv   = t >> 6;
    const int wm   = (wv >> 1) * 64;
    const int wn   = (wv & 1) * 64;
    const int m0   = blockIdx.y * BM;
    const int n0   = blockIdx.x * BN;

    f32x4 acc[4][4] = {};

    const int lrow = lane >> 3;        // 0..7  row within 8-row wave stripe
    const int lch  = (lane & 7) * 8;   // 16B chunk (ushort offset)

    // prologue: stage k0=0 into buf 0
    #pragma unroll
    for (int i = 0; i < 4; ++i) {
        const int rb = i * 32 + wv * 8;          // wave-uniform row base
        gload16(&A[(size_t)(m0 + rb + lrow) * DIM + lch], &Ah[0][rb][0]);
        gload16(&B[(size_t)(n0 + rb + lrow) * DIM + lch], &Bh[0][rb][0]);
    }
    __syncthreads();

    int cur = 0;
    for (int k0 = 0; k0 < DIM; k0 += BK) {
        if (k0 + BK < DIM) {       // prefetch next K-tile into buf^1
            #pragma unroll
            for (int i = 0; i < 4; ++i) {
                const int rb = i * 32 + wv * 8;
                gload16(&A[(size_t)(m0 + rb + lrow) * DIM + k0 + BK + lch],
                        &Ah[cur ^ 1][rb][0]);
                gload16(&B[(size_t)(n0 + rb + lrow) * DIM + k0 + BK + lch],
                        &Bh[cur ^ 1][rb][0]);
            }
        }

        #pragma unroll
        for (int ks = 0; ks < BK; ks += 32) {
            const int koff = ks + ((lane >> 4) << 3);
            const int rs = lane & 15;
            bf16x8 af[4], bf[4];
            #pragma unroll
            for (int i = 0; i < 4; ++i) {
                af[i] = *(const bf16x8*)&Ah[cur][wm + i * 16 + rs][koff];
                bf[i] = *(const bf16x8*)&Bh[cur][wn + i * 16 + rs][koff];
            }
            #pragma unroll
            for (int i = 0; i < 4; ++i)
                #pragma unroll
                for (int j = 0; j < 4; ++j)
                    acc[i][j] = __builtin_amdgcn_mfma_f32_16x16x32_bf16(
                        af[i], bf[j], acc[i][j], 0, 0, 0);
        }
        __syncthreads();   // drains vmcnt (prefetch landed, hidden) + lgkm;
        cur ^= 1;          // all waves done reading old buf
    }

    const int rsel  = lane & 15;
    const int quad  = lane >> 4;
    const int rbase = m0 + wm + (quad << 2);
    const int c0    = n0 + wn;          // 64-aligned -> one (t,h) per wave
    const int tt    = c0 / DIM;
    const int h     = (c0 % DIM) >> 6;

    if (tt == 2) {
        // key kappa (within 64-tile) = 16i + 4quad + r
        // -> slot 32*(i>>1) + 8*quad + 4*(i&1) + r   (swapped-PV order)
        const int T = (m0 + wm) >> 6;
        #pragma unroll
        for (int j = 0; j < 4; ++j) {
            const int d = rsel + 16 * j;
            ushort vvA[8], vvB[8];
            #pragma unroll
            for (int i2 = 0; i2 < 2; ++i2)
                #pragma unroll
                for (int r = 0; r < 4; ++r) {
                    vvA[4 * i2 + r] = f2bf(acc[i2][j][r]);        // i=0,1 -> c=0
                    vvB[4 * i2 + r] = f2bf(acc[2 + i2][j][r]);    // i=2,3 -> c=1
                }
            ushort* dst = &Vp[((size_t)h * HD + d) * SEQ + T * 64];
            *(float4*)&dst[8 * quad]      = *(const float4*)&vvA[0];
            *(float4*)&dst[32 + 8 * quad] = *(const float4*)&vvB[0];
        }
    } else {
        ushort* dstb = (tt == 0 ? Qb : Kb) + (size_t)h * SEQ * HD;
        // 0.125 * log2(e): flash computes exp(S) via v_exp_f32 (2^S').
        const float qs = (tt == 0) ? 0.18033688011112042f : 1.0f;
        #pragma unroll
        for (int i = 0; i < 4; ++i)
            #pragma unroll
            for (int r = 0; r < 4; ++r) {
                const int n = rbase + i * 16 + r;
                #pragma unroll
                for (int j = 0; j < 2; ++j) {
                    const float a = acc[i][j][r];
                    const float b = acc[i][j + 2][r];
                    const float2 cs2 = tab[n * 32 + rsel + 16 * j];
                    dstb[(size_t)n * HD + rsel + 16 * j]      = f2bf((a * cs2.x - b * cs2.y) * qs);
                    dstb[(size_t)n * HD + rsel + 16 * j + 32] = f2bf((b * cs2.x + a * cs2.y) * qs);
                }
            }
    }
}

// ---------------------------------------------------------------------------
// MFMA flash attention — SWAPPED QK^T, register-slim edition.
// r12 post-mortem: allocator cap ≈ 256/min_waves ((256,3)->84, (256,2)->128
// from r10/r12 counters); swapped kernel's ~150-reg demand spilled at 84.
// This version cuts peak-live to ~112 so (256,2)'s 128 cap fits:
//   * QK^T loop INVERTED (ks,n outer / mi inner): bk fragment loaded once,
//     feeds both mi MFMAs, dies immediately — no persistent bk[4][2] (-32).
//   * PV j-outer with TRANSIENT bv loads: bv0/bv1 loaded per j, feed all 4
//     MFMAs (both mi), die — no persistent bv[4][2] (-32).
//   * accS[2][4] (both mi) = +16; net -48 vs r12.
// P still never touches LDS (exp -> RNE tw -> u32x4 literal -> bit_cast).
// LDS 34.8 KB; VGPR <=128 -> up to 4 blocks/CU (139 KB LDS < 160).
// T1 XCD swizzle + T3 1-barrier dbuf retained.
// ---------------------------------------------------------------------------
__global__ __launch_bounds__(256, 2)
void flash_mfma(const ushort* __restrict__ Qb, const ushort* __restrict__ Kb,
                const ushort* __restrict__ Vp,
                float* __restrict__ Opart, float* __restrict__ lpart)
{
    __shared__ ushort Ks[2][64][68];   // [buf][key][d]
    __shared__ ushort Vs[2][64][68];   // [buf][d][slot]

    const int t    = threadIdx.x;
    const int lane = t & 63;
    const int wv   = t >> 6;
    const int rsel = lane & 15;
    const int quad = lane >> 4;

    // T1 XCD swizzle: 768 blocks; 32 q-tiles per (h,part) group, 24 groups.
    const int p  = blockIdx.x + 32 * (blockIdx.y + 12 * blockIdx.z);
    const int c  = p & 7;              // xcd slot
    const int r  = p >> 3;             // 0..95 position within xcd
    const int gi = r >> 5;             // 0..2  group index within xcd
    const int xq = r & 31;             // q-tile
    const int g  = gi * 8 + c;         // 0..23 (h,part) group
    const int h    = g % 12;
    const int part = g / 12;

    const int q0   = xq * 128 + wv * 32;
    const int Tbeg = (part * (SEQ / KSPLIT)) >> 6;
    const int Tend = Tbeg + (SEQ / KSPLIT) / 64;   // 32 tiles

    const int crow = t >> 2;           // 0..63 staging row
    const int ccol = (t & 3) * 16;     // 0/16/32/48 ushorts (2x16B per thread)

    // Q B-frags (persistent): lane holds Q[q=16mi+rsel][32ks + quad*8 ..]
    bf16x8 aq[2][2];
    #pragma unroll
    for (int mi = 0; mi < 2; ++mi)
        #pragma unroll
        for (int ks = 0; ks < 2; ++ks)
            aq[mi][ks] = *(const bf16x8*)&Qb[((size_t)h * SEQ + q0 + 16 * mi + rsel) * HD
                                             + ks * 32 + quad * 8];

    f32x4 accO[2][4] = {};
    float lsum[2] = {0.f, 0.f};

    // prologue: stage tile Tbeg into buf 0
    {
        const ushort* ksrc = &Kb[((size_t)h * SEQ + Tbeg * 64 + crow) * HD + ccol];
        const float4 k0 = *(const float4*)&ksrc[0];
        const float4 k1 = *(const float4*)&ksrc[8];
        const ushort* vsrc = &Vp[((size_t)h * HD + crow) * SEQ + Tbeg * 64 + ccol];
        const float4 v0 = *(const float4*)&vsrc[0];
        const float4 v1 = *(const float4*)&vsrc[8];
        *(float4*)&Ks[0][crow][ccol]     = k0;
        *(float4*)&Ks[0][crow][ccol + 8] = k1;
        *(float4*)&Vs[0][crow][ccol]     = v0;
        *(float4*)&Vs[0][crow][ccol + 8] = v1;
    }
    __syncthreads();

    int cur = 0;
    for (int T = Tbeg; T < Tend; ++T) {
        // issue next-tile K/V loads (clamped on last iter; L2-hot, harmless).
        const int Tn = (T + 1 < Tend) ? T + 1 : T;
        const ushort* ksrc = &Kb[((size_t)h * SEQ + Tn * 64 + crow) * HD + ccol];
        const float4 kn0 = *(const float4*)&ksrc[0];
        const float4 kn1 = *(const float4*)&ksrc[8];
        const ushort* vsrc = &Vp[((size_t)h * HD + crow) * SEQ + Tn * 64 + ccol];
        const float4 vn0 = *(const float4*)&vsrc[0];
        const float4 vn1 = *(const float4*)&vsrc[8];

        // ---- QK^T, both mi at once; bk fragments are transient ----
        // accS[mi][n] holds S[key=16n+4quad+r][q=16mi+rsel]
        f32x4 accS[2][4] = {};
        __builtin_amdgcn_s_setprio(1);
        #pragma unroll
        for (int ks = 0; ks < 2; ++ks)
            #pragma unroll
            for (int n = 0; n < 4; ++n) {
                const bf16x8 bk =
                    *(const bf16x8*)&Ks[cur][16 * n + rsel][32 * ks + quad * 8];
                accS[0][n] = __builtin_amdgcn_mfma_f32_16x16x32_bf16(
                    bk, aq[0][ks], accS[0][n], 0, 0, 0);
                accS[1][n] = __builtin_amdgcn_mfma_f32_16x16x32_bf16(
                    bk, aq[1][ks], accS[1][n], 0, 0, 0);
            }
        __builtin_amdgcn_s_setprio(0);

        // ---- P = 2^S; pack PV A-frags in registers (no alloca) ----
        bf16x8 ap[2][2];
        #pragma unroll
        for (int mi = 0; mi < 2; ++mi) {
            const float p00 = __builtin_amdgcn_exp2f(accS[mi][0][0]);
            const float p01 = __builtin_amdgcn_exp2f(accS[mi][0][1]);
            const float p02 = __builtin_amdgcn_exp2f(accS[mi][0][2]);
            const float p03 = __builtin_amdgcn_exp2f(accS[mi][0][3]);
            const float p10 = __builtin_amdgcn_exp2f(accS[mi][1][0]);
            const float p11 = __builtin_amdgcn_exp2f(accS[mi][1][1]);
            const float p12 = __builtin_amdgcn_exp2f(accS[mi][1][2]);
            const float p13 = __builtin_amdgcn_exp2f(accS[mi][1][3]);
            const float p20 = __builtin_amdgcn_exp2f(accS[mi][2][0]);
            const float p21 = __builtin_amdgcn_exp2f(accS[mi][2][1]);
            const float p22 = __builtin_amdgcn_exp2f(accS[mi][2][2]);
            const float p23 = __builtin_amdgcn_exp2f(accS[mi][2][3]);
            const float p30 = __builtin_amdgcn_exp2f(accS[mi][3][0]);
            const float p31 = __builtin_amdgcn_exp2f(accS[mi][3][1]);
            const float p32 = __builtin_amdgcn_exp2f(accS[mi][3][2]);
            const float p33 = __builtin_amdgcn_exp2f(accS[mi][3][3]);

            const u32x4 aw0 = {
                (uint)f2bf_tw(p00) | ((uint)f2bf_tw(p01) << 16),
                (uint)f2bf_tw(p02) | ((uint)f2bf_tw(p03) << 16),
                (uint)f2bf_tw(p10) | ((uint)f2bf_tw(p11) << 16),
                (uint)f2bf_tw(p12) | ((uint)f2bf_tw(p13) << 16) };
            const u32x4 aw1 = {
                (uint)f2bf_tw(p20) | ((uint)f2bf_tw(p21) << 16),
                (uint)f2bf_tw(p22) | ((uint)f2bf_tw(p23) << 16),
                (uint)f2bf_tw(p30) | ((uint)f2bf_tw(p31) << 16),
                (uint)f2bf_tw(p32) | ((uint)f2bf_tw(p33) << 16) };
            ap[mi][0] = __builtin_bit_cast(bf16x8, aw0);
            ap[mi][1] = __builtin_bit_cast(bf16x8, aw1);

            lsum[mi] += ((p00 + p01) + (p02 + p03)) + ((p10 + p11) + (p12 + p13))
                      + ((p20 + p21) + (p22 + p23)) + ((p30 + p31) + (p32 + p33));
        }

        // ---- PV, j-outer; bv fragments are transient ----
        __builtin_amdgcn_s_setprio(1);
        #pragma unroll
        for (int j = 0; j < 4; ++j) {
            const bf16x8 bv0 = *(const bf16x8*)&Vs[cur][16 * j + rsel][quad * 8];
            const bf16x8 bv1 = *(const bf16x8*)&Vs[cur][16 * j + rsel][32 + quad * 8];
            accO[0][j] = __builtin_amdgcn_mfma_f32_16x16x32_bf16(
                ap[0][0], bv0, accO[0][j], 0, 0, 0);
            accO[0][j] = __builtin_amdgcn_mfma_f32_16x16x32_bf16(
                ap[0][1], bv1, accO[0][j], 0, 0, 0);
            accO[1][j] = __builtin_amdgcn_mfma_f32_16x16x32_bf16(
                ap[1][0], bv0, accO[1][j], 0, 0, 0);
            accO[1][j] = __builtin_amdgcn_mfma_f32_16x16x32_bf16(
                ap[1][1], bv1, accO[1][j], 0, 0, 0);
        }
        __builtin_amdgcn_s_setprio(0);

        // write staged tile T+1 into buf[cur^1] (vmcnt wait lands here —
        // loads issued a full tile ago; cur^1 dead since prior barrier).
        *(float4*)&Ks[cur ^ 1][crow][ccol]     = kn0;
        *(float4*)&Ks[cur ^ 1][crow][ccol + 8] = kn1;
        *(float4*)&Vs[cur ^ 1][crow][ccol]     = vn0;
        *(float4*)&Vs[cur ^ 1][crow][ccol + 8] = vn1;
        __syncthreads();               // drains ds_writes, publishes buf[cur^1]
        cur ^= 1;
    }

    // l reduction across the 4 quads (lanes l, l^16, l^32, l^48 share q=rsel)
    #pragma unroll
    for (int mi = 0; mi < 2; ++mi) {
        float s = lsum[mi];
        s += __shfl_xor(s, 16);
        s += __shfl_xor(s, 32);
        lsum[mi] = s;
    }

    float* Ob = Opart + ((size_t)part * NHEADS + h) * SEQ * HD;
    float* lb = lpart + ((size_t)part * NHEADS + h) * SEQ;
    #pragma unroll
    for (int mi = 0; mi < 2; ++mi) {
        #pragma unroll
        for (int r = 0; r < 4; ++r) {
            const int n = q0 + 16 * mi + 4 * quad + r;
            #pragma unroll
            for (int j = 0; j < 4; ++j)
                Ob[(size_t)n * HD + 16 * j + rsel] = accO[mi][j][r];
        }
        if (quad == 0) lb[q0 + 16 * mi + rsel] = lsum[mi];
    }
}

// ---------------------------------------------------------------------------
// Split-K merge: AO[n][h*64+d] = (sum_p Opart) / (sum_p l), bf16.
// ---------------------------------------------------------------------------
__global__ __launch_bounds__(256)
void merge_k(const float* __restrict__ Opart, const float* __restrict__ lpart,
             ushort* __restrict__ AO)
{
    const int idx = blockIdx.x * 256 + threadIdx.x;
    const int dg = idx & 15;
    const int n  = (idx >> 4) & (SEQ - 1);
    const int h  = idx >> 16;

    float4 o = make_float4(0.f, 0.f, 0.f, 0.f);
    float l = 0.f;
    #pragma unroll
    for (int p = 0; p < KSPLIT; ++p) {
        const float4 v = *(const float4*)&Opart[(((size_t)p * NHEADS + h) * SEQ + n) * HD + dg * 4];
        o.x += v.x; o.y += v.y; o.z += v.z; o.w += v.w;
        l += lpart[((size_t)p * NHEADS + h) * SEQ + n];
    }
    const float inv = 1.f / l;
    ushort4 w;
    w.x = f2bf(o.x * inv); w.y = f2bf(o.y * inv);
    w.z = f2bf(o.z * inv); w.w = f2bf(o.w * inv);
    *(ushort4*)&AO[(size_t)n * DIM + h * HD + dg * 4] = w;
}

// ---------------------------------------------------------------------------
// Proj GEMM: out = attnout(bf16) @ proj_wb(bf16)^T + proj_b(f32), f32 out.
// T3 1-barrier double-buffered K-loop (same as gemm_qkv).
// ---------------------------------------------------------------------------
__global__ __launch_bounds__(256)
void gemm_proj(const ushort* __restrict__ A, const ushort* __restrict__ B,
               const float* __restrict__ bias, float* __restrict__ out)
{
    constexpr int BM = 128, BN = 128, BK = 64;
    __shared__ __attribute__((aligned(16))) ushort As[2][BM][BK];
    __shared__ __attribute__((aligned(16))) ushort Bs[2][BN][BK];

    const int t    = threadIdx.x;
    const int lane = t & 63;
    const int wv   = t >> 6;
    const int wm   = (wv >> 1) * 64;
    const int wn   = (wv & 1) * 64;
    const int m0   = blockIdx.y * BM;
    const int n0   = blockIdx.x * BN;

    f32x4 acc[4][4] = {};

    const int lrow = lane >> 3;
    const int lch  = (lane & 7) * 8;

    #pragma unroll
    for (int i = 0; i < 4; ++i) {
        const int rb = i * 32 + wv * 8;
        gload16(&A[(size_t)(m0 + rb + lrow) * DIM + lch], &As[0][rb][0]);
        gload16(&B[(size_t)(n0 + rb + lrow) * DIM + lch], &Bs[0][rb][0]);
    }
    __syncthreads();

    int cur = 0;
    for (int k0 = 0; k0 < DIM; k0 += BK) {
        if (k0 + BK < DIM) {
            #pragma unroll
            for (int i = 0; i < 4; ++i) {
                const int rb = i * 32 + wv * 8;
                gload16(&A[(size_t)(m0 + rb + lrow) * DIM + k0 + BK + lch],
                        &As[cur ^ 1][rb][0]);
                gload16(&B[(size_t)(n0 + rb + lrow) * DIM + k0 + BK + lch],
                        &Bs[cur ^ 1][rb][0]);
            }
        }

        #pragma unroll
        for (int ks = 0; ks < BK; ks += 32) {
            const int koff = ks + ((lane >> 4) << 3);
            const int rs = lane & 15;
            bf16x8 af[4], bf[4];
            #pragma unroll
            for (int i = 0; i < 4; ++i) {
                af[i] = *(const bf16x8*)&As[cur][wm + i * 16 + rs][koff];
                bf[i] = *(const bf16x8*)&Bs[cur][wn + i * 16 + rs][koff];
            }
            #pragma unroll
            for (int i = 0; i < 4; ++i)
                #pragma unroll
                for (int j = 0; j < 4; ++j)
                    acc[i][j] = __builtin_amdgcn_mfma_f32_16x16x32_bf16(
                        af[i], bf[j], acc[i][j], 0, 0, 0);
        }
        __syncthreads();
        cur ^= 1;
    }

    const int rbase = m0 + wm + ((lane >> 4) << 2);
    const int cbase = n0 + wn + (lane & 15);

    #pragma unroll
    for (int j = 0; j < 4; ++j) {
        const int col = cbase + j * 16;
        const float bv = bias[col];
        #pragma unroll
        for (int i = 0; i < 4; ++i) {
            const int row0 = rbase + i * 16;
            #pragma unroll
            for (int r = 0; r < 4; ++r)
                out[(size_t)(row0 + r) * DIM + col] = acc[i][j][r] + bv;
        }
    }
}

// ---------------------------------------------------------------------------
extern "C" void kernel_launch(void* const* d_in, const int* in_sizes, int n_in,
                              void* d_out, int out_size, void* d_ws, size_t ws_size,
                              hipStream_t stream)
{
    const float* x      = (const float*)d_in[0];
    const float* qkv_w  = (const float*)d_in[1];
    const float* proj_w = (const float*)d_in[2];
    const float* proj_b = (const float*)d_in[3];

    const size_t headsz = (size_t)NHEADS * SEQ * HD;       // 3,145,728
    char* p = (char*)d_ws;
    ushort* Qb    = (ushort*)p;                 p += headsz * 2;
    ushort* Kb    = (ushort*)p;                 p += headsz * 2;
    ushort* Vp    = (ushort*)p;                 p += headsz * 2;
    ushort* AO    = (ushort*)p;                 p += (size_t)SEQ * DIM * 2;
    float*  Opart = (float*)p;                  p += (size_t)KSPLIT * headsz * 4;
    float*  lpart = (float*)p;                  p += (size_t)KSPLIT * NHEADS * SEQ * 4;
    float2* tab   = (float2*)p;                 p += (size_t)SEQ * 32 * sizeof(float2);
    ushort* xb    = (ushort*)p;                 p += (size_t)SEQ * DIM * 2;
    ushort* qwb   = (ushort*)p;                 p += (size_t)3 * DIM * DIM * 2;
    ushort* pwb   = (ushort*)p;
    float*  out   = (float*)d_out;

    prep<<<5888, 256, 0, stream>>>(x, qkv_w, proj_w, xb, qwb, pwb, tab);

    gemm_qkv<<<dim3(3 * DIM / 128, SEQ / 128), 256, 0, stream>>>(
        xb, qwb, tab, Qb, Kb, Vp);

    flash_mfma<<<dim3(SEQ / 128, NHEADS, KSPLIT), 256, 0, stream>>>(
        Qb, Kb, Vp, Opart, lpart);

    merge_k<<<(NHEADS * SEQ * 16) / 256, 256, 0, stream>>>(Opart, lpart, AO);

    gemm_proj<<<dim3(DIM / 128, SEQ / 128), 256, 0, stream>>>(
        AO, pwb, proj_b, out);
}

// Round 14
// 185.221 us; speedup vs baseline: 1.2838x; 1.1104x over previous
//
#include <hip/hip_runtime.h>
#include <hip/hip_bf16.h>
#include <math.h>

#define DIM 768
#define NHEADS 12
#define HD 64
#define SEQ 4096
#define KSPLIT 2

typedef __bf16 bf16x8 __attribute__((ext_vector_type(8)));
typedef float f32x4 __attribute__((ext_vector_type(4)));
typedef uint  u32x4 __attribute__((ext_vector_type(4)));

// Native bf16 convert (RNE) — used outside flash.
__device__ inline ushort f2bf(float f) {
    __bf16 b = (__bf16)f;
    union { __bf16 b; ushort u; } v; v.b = b;
    return v.u;
}

// Packed f32->bf16 pair convert (one VALU op). Rounding may be biased
// (truncation-like, r1 ERRATA) — ONLY valid when the softmax denominator
// is computed from the SAME rounded values so the bias cancels in the
// ratio (this round's MFMA-ones lsum does exactly that).
__device__ inline uint cvt_pk_bf16(float lo, float hi) {
    uint r;
    asm("v_cvt_pk_bf16_f32 %0, %1, %2" : "=v"(r) : "v"(lo), "v"(hi));
    return r;
}

// global -> LDS direct copy, 16B per lane. LDS dest is WAVE-UNIFORM base
// (hw adds lane*16); global src is per-lane.
__device__ inline void gload16(const ushort* gsrc, ushort* lbase) {
    __builtin_amdgcn_global_load_lds(
        (const __attribute__((address_space(1))) uint*)gsrc,
        (__attribute__((address_space(3))) uint*)lbase, 16, 0, 0);
}

// ---------------------------------------------------------------------------
// Fused prologue: block-range dispatch over
//   [0,3072)    : x f32 -> bf16            (4096*768 /4 /256)
//   [3072,4800) : qkv_w f32 -> bf16        (3*768*768 /4 /256)
//   [4800,5376) : proj_w f32 -> bf16       (768*768 /4 /256)
//   [5376,5888) : RoPE table tab[n][j]     (4096*32 /256)
// ---------------------------------------------------------------------------
__global__ __launch_bounds__(256)
void prep(const float* __restrict__ x, const float* __restrict__ qkv_w,
          const float* __restrict__ proj_w,
          ushort* __restrict__ xb, ushort* __restrict__ qwb,
          ushort* __restrict__ pwb, float2* __restrict__ tab)
{
    const int b = blockIdx.x;
    if (b < 5376) {
        const float* src; ushort* dst; int i;
        if (b < 3072)      { src = x;      dst = xb;  i = b * 256 + threadIdx.x; }
        else if (b < 4800) { src = qkv_w;  dst = qwb; i = (b - 3072) * 256 + threadIdx.x; }
        else               { src = proj_w; dst = pwb; i = (b - 4800) * 256 + threadIdx.x; }
        const float4 v = ((const float4*)src)[i];
        ushort4 w;
        w.x = f2bf(v.x); w.y = f2bf(v.y); w.z = f2bf(v.z); w.w = f2bf(v.w);
        ((ushort4*)dst)[i] = w;
    } else {
        const int idx = (b - 5376) * 256 + threadIdx.x;   // 4096*32
        const int j = idx & 31;
        const int n = idx >> 5;
        const float invf = (float)pow(10000.0, -(double)j / 32.0);
        const float ang  = (float)n * invf;               // f32 (matches ref freqs)
        double s, c;
        sincos((double)ang, &s, &c);
        tab[idx] = make_float2((float)c, (float)s);
    }
}

// ---------------------------------------------------------------------------
// QKV GEMM (bf16 in) + fused RoPE + layout. T3 1-barrier double-buffered
// K-loop. LDS 64 KB -> 2 blocks/CU.
//   t=0 (q): RoPE, *0.125*log2e (exp->exp2 fold), bf16 -> Qb[h][n][d]
//   t=1 (k): RoPE, bf16 -> Kb[h][n][d]
//   t=2 (v): bf16 -> Vp[h][d][64T + slot], slot permuted for the SWAPPED-
//            QK^T flash PV path: key kappa=16i+4quad+r -> slot
//            32*(i>>1) + 8*quad + 4*(i&1) + r  (so flash's in-register P
//            fragments [p(n=2c)[0..3], p(2c+1)[0..3]] multiply V directly).
// ---------------------------------------------------------------------------
__global__ __launch_bounds__(256)
void gemm_qkv(const ushort* __restrict__ A, const ushort* __restrict__ B,
              const float2* __restrict__ tab,
              ushort* __restrict__ Qb, ushort* __restrict__ Kb,
              ushort* __restrict__ Vp)
{
    constexpr int BM = 128, BN = 128, BK = 64;
    __shared__ __attribute__((aligned(16))) ushort Ah[2][BM][BK];
    __shared__ __attribute__((aligned(16))) ushort Bh[2][BN][BK];

    const int t    = threadIdx.x;
    const int lane = t & 63;
    const int wv   = t >> 6;
    const int wm   = (wv >> 1) * 64;
    const int wn   = (wv & 1) * 64;
    const int m0   = blockIdx.y * BM;
    const int n0   = blockIdx.x * BN;

    f32x4 acc[4][4] = {};

    const int lrow = lane >> 3;        // 0..7  row within 8-row wave stripe
    const int lch  = (lane & 7) * 8;   // 16B chunk (ushort offset)

    // prologue: stage k0=0 into buf 0
    #pragma unroll
    for (int i = 0; i < 4; ++i) {
        const int rb = i * 32 + wv * 8;          // wave-uniform row base
        gload16(&A[(size_t)(m0 + rb + lrow) * DIM + lch], &Ah[0][rb][0]);
        gload16(&B[(size_t)(n0 + rb + lrow) * DIM + lch], &Bh[0][rb][0]);
    }
    __syncthreads();

    int cur = 0;
    for (int k0 = 0; k0 < DIM; k0 += BK) {
        if (k0 + BK < DIM) {       // prefetch next K-tile into buf^1
            #pragma unroll
            for (int i = 0; i < 4; ++i) {
                const int rb = i * 32 + wv * 8;
                gload16(&A[(size_t)(m0 + rb + lrow) * DIM + k0 + BK + lch],
                        &Ah[cur ^ 1][rb][0]);
                gload16(&B[(size_t)(n0 + rb + lrow) * DIM + k0 + BK + lch],
                        &Bh[cur ^ 1][rb][0]);
            }
        }

        #pragma unroll
        for (int ks = 0; ks < BK; ks += 32) {
            const int koff = ks + ((lane >> 4) << 3);
            const int rs = lane & 15;
            bf16x8 af[4], bf[4];
            #pragma unroll
            for (int i = 0; i < 4; ++i) {
                af[i] = *(const bf16x8*)&Ah[cur][wm + i * 16 + rs][koff];
                bf[i] = *(const bf16x8*)&Bh[cur][wn + i * 16 + rs][koff];
            }
            #pragma unroll
            for (int i = 0; i < 4; ++i)
                #pragma unroll
                for (int j = 0; j < 4; ++j)
                    acc[i][j] = __builtin_amdgcn_mfma_f32_16x16x32_bf16(
                        af[i], bf[j], acc[i][j], 0, 0, 0);
        }
        __syncthreads();   // drains vmcnt (prefetch landed, hidden) + lgkm;
        cur ^= 1;          // all waves done reading old buf
    }

    const int rsel  = lane & 15;
    const int quad  = lane >> 4;
    const int rbase = m0 + wm + (quad << 2);
    const int c0    = n0 + wn;          // 64-aligned -> one (t,h) per wave
    const int tt    = c0 / DIM;
    const int h     = (c0 % DIM) >> 6;

    if (tt == 2) {
        // key kappa (within 64-tile) = 16i + 4quad + r
        // -> slot 32*(i>>1) + 8*quad + 4*(i&1) + r   (swapped-PV order)
        const int T = (m0 + wm) >> 6;
        #pragma unroll
        for (int j = 0; j < 4; ++j) {
            const int d = rsel + 16 * j;
            ushort vvA[8], vvB[8];
            #pragma unroll
            for (int i2 = 0; i2 < 2; ++i2)
                #pragma unroll
                for (int r = 0; r < 4; ++r) {
                    vvA[4 * i2 + r] = f2bf(acc[i2][j][r]);        // i=0,1 -> c=0
                    vvB[4 * i2 + r] = f2bf(acc[2 + i2][j][r]);    // i=2,3 -> c=1
                }
            ushort* dst = &Vp[((size_t)h * HD + d) * SEQ + T * 64];
            *(float4*)&dst[8 * quad]      = *(const float4*)&vvA[0];
            *(float4*)&dst[32 + 8 * quad] = *(const float4*)&vvB[0];
        }
    } else {
        ushort* dstb = (tt == 0 ? Qb : Kb) + (size_t)h * SEQ * HD;
        // 0.125 * log2(e): flash computes exp(S) via v_exp_f32 (2^S').
        const float qs = (tt == 0) ? 0.18033688011112042f : 1.0f;
        #pragma unroll
        for (int i = 0; i < 4; ++i)
            #pragma unroll
            for (int r = 0; r < 4; ++r) {
                const int n = rbase + i * 16 + r;
                #pragma unroll
                for (int j = 0; j < 2; ++j) {
                    const float a = acc[i][j][r];
                    const float b = acc[i][j + 2][r];
                    const float2 cs2 = tab[n * 32 + rsel + 16 * j];
                    dstb[(size_t)n * HD + rsel + 16 * j]      = f2bf((a * cs2.x - b * cs2.y) * qs);
                    dstb[(size_t)n * HD + rsel + 16 * j + 32] = f2bf((b * cs2.x + a * cs2.y) * qs);
                }
            }
    }
}

// ---------------------------------------------------------------------------
// MFMA flash attention — SWAPPED QK^T, register-slim (r13: 76.5us, no
// spill) + packed-convert softmax:
//   * P f32->bf16 via v_cvt_pk_bf16_f32 (1 op / 2 values; replaces the
//     7-op/pair RNE twiddle). Its rounding bias is cancelled by computing
//     the denominator FROM THE SAME ROUNDED VALUES:
//   * lsum via MFMA with all-ones B: accL = mfma(ap, ones) = row-sums of
//     the bf16 P that the PV path consumes. Numerator and denominator are
//     consistent, so the systematic rounding component cancels in the
//     softmax ratio (r1's 4.3e-2 failure was biased-P / UNBIASED-f32-l).
//     Also deletes the 32 f32 lsum adds + the shfl_xor quad reduction.
// VALU per tile: ~420cy -> ~210cy (32 exp2 + 16 cvt_pk + addressing).
// Everything else identical to r13 (transient bk/bv, 1-barrier dbuf,
// T1 XCD swizzle, LDS 34.8 KB, (256,2) -> 128-reg cap, ~80 live).
// ---------------------------------------------------------------------------
__global__ __launch_bounds__(256, 2)
void flash_mfma(const ushort* __restrict__ Qb, const ushort* __restrict__ Kb,
                const ushort* __restrict__ Vp,
                float* __restrict__ Opart, float* __restrict__ lpart)
{
    __shared__ ushort Ks[2][64][68];   // [buf][key][d]
    __shared__ ushort Vs[2][64][68];   // [buf][d][slot]

    const int t    = threadIdx.x;
    const int lane = t & 63;
    const int wv   = t >> 6;
    const int rsel = lane & 15;
    const int quad = lane >> 4;

    // T1 XCD swizzle: 768 blocks; 32 q-tiles per (h,part) group, 24 groups.
    const int p  = blockIdx.x + 32 * (blockIdx.y + 12 * blockIdx.z);
    const int c  = p & 7;              // xcd slot
    const int r  = p >> 3;             // 0..95 position within xcd
    const int gi = r >> 5;             // 0..2  group index within xcd
    const int xq = r & 31;             // q-tile
    const int g  = gi * 8 + c;         // 0..23 (h,part) group
    const int h    = g % 12;
    const int part = g / 12;

    const int q0   = xq * 128 + wv * 32;
    const int Tbeg = (part * (SEQ / KSPLIT)) >> 6;
    const int Tend = Tbeg + (SEQ / KSPLIT) / 64;   // 32 tiles

    const int crow = t >> 2;           // 0..63 staging row
    const int ccol = (t & 3) * 16;     // 0/16/32/48 ushorts (2x16B per thread)

    // Q B-frags (persistent): lane holds Q[q=16mi+rsel][32ks + quad*8 ..]
    bf16x8 aq[2][2];
    #pragma unroll
    for (int mi = 0; mi < 2; ++mi)
        #pragma unroll
        for (int ks = 0; ks < 2; ++ks)
            aq[mi][ks] = *(const bf16x8*)&Qb[((size_t)h * SEQ + q0 + 16 * mi + rsel) * HD
                                             + ks * 32 + quad * 8];

    // all-ones bf16 B operand for the lsum row-sum MFMA
    const u32x4 onesw = { 0x3F803F80u, 0x3F803F80u, 0x3F803F80u, 0x3F803F80u };
    const bf16x8 ones = __builtin_bit_cast(bf16x8, onesw);

    f32x4 accO[2][4] = {};
    f32x4 accL[2] = {};                // row-sums of bf16 P (denominator)

    // prologue: stage tile Tbeg into buf 0
    {
        const ushort* ksrc = &Kb[((size_t)h * SEQ + Tbeg * 64 + crow) * HD + ccol];
        const float4 k0 = *(const float4*)&ksrc[0];
        const float4 k1 = *(const float4*)&ksrc[8];
        const ushort* vsrc = &Vp[((size_t)h * HD + crow) * SEQ + Tbeg * 64 + ccol];
        const float4 v0 = *(const float4*)&vsrc[0];
        const float4 v1 = *(const float4*)&vsrc[8];
        *(float4*)&Ks[0][crow][ccol]     = k0;
        *(float4*)&Ks[0][crow][ccol + 8] = k1;
        *(float4*)&Vs[0][crow][ccol]     = v0;
        *(float4*)&Vs[0][crow][ccol + 8] = v1;
    }
    __syncthreads();

    int cur = 0;
    for (int T = Tbeg; T < Tend; ++T) {
        // issue next-tile K/V loads (clamped on last iter; L2-hot, harmless).
        const int Tn = (T + 1 < Tend) ? T + 1 : T;
        const ushort* ksrc = &Kb[((size_t)h * SEQ + Tn * 64 + crow) * HD + ccol];
        const float4 kn0 = *(const float4*)&ksrc[0];
        const float4 kn1 = *(const float4*)&ksrc[8];
        const ushort* vsrc = &Vp[((size_t)h * HD + crow) * SEQ + Tn * 64 + ccol];
        const float4 vn0 = *(const float4*)&vsrc[0];
        const float4 vn1 = *(const float4*)&vsrc[8];

        // ---- QK^T, both mi at once; bk fragments are transient ----
        // accS[mi][n] holds S[key=16n+4quad+r][q=16mi+rsel]
        f32x4 accS[2][4] = {};
        __builtin_amdgcn_s_setprio(1);
        #pragma unroll
        for (int ks = 0; ks < 2; ++ks)
            #pragma unroll
            for (int n = 0; n < 4; ++n) {
                const bf16x8 bk =
                    *(const bf16x8*)&Ks[cur][16 * n + rsel][32 * ks + quad * 8];
                accS[0][n] = __builtin_amdgcn_mfma_f32_16x16x32_bf16(
                    bk, aq[0][ks], accS[0][n], 0, 0, 0);
                accS[1][n] = __builtin_amdgcn_mfma_f32_16x16x32_bf16(
                    bk, aq[1][ks], accS[1][n], 0, 0, 0);
            }
        __builtin_amdgcn_s_setprio(0);

        // ---- P = 2^S; packed convert to PV A-frags (registers only) ----
        bf16x8 ap[2][2];
        #pragma unroll
        for (int mi = 0; mi < 2; ++mi) {
            const float p00 = __builtin_amdgcn_exp2f(accS[mi][0][0]);
            const float p01 = __builtin_amdgcn_exp2f(accS[mi][0][1]);
            const float p02 = __builtin_amdgcn_exp2f(accS[mi][0][2]);
            const float p03 = __builtin_amdgcn_exp2f(accS[mi][0][3]);
            const float p10 = __builtin_amdgcn_exp2f(accS[mi][1][0]);
            const float p11 = __builtin_amdgcn_exp2f(accS[mi][1][1]);
            const float p12 = __builtin_amdgcn_exp2f(accS[mi][1][2]);
            const float p13 = __builtin_amdgcn_exp2f(accS[mi][1][3]);
            const float p20 = __builtin_amdgcn_exp2f(accS[mi][2][0]);
            const float p21 = __builtin_amdgcn_exp2f(accS[mi][2][1]);
            const float p22 = __builtin_amdgcn_exp2f(accS[mi][2][2]);
            const float p23 = __builtin_amdgcn_exp2f(accS[mi][2][3]);
            const float p30 = __builtin_amdgcn_exp2f(accS[mi][3][0]);
            const float p31 = __builtin_amdgcn_exp2f(accS[mi][3][1]);
            const float p32 = __builtin_amdgcn_exp2f(accS[mi][3][2]);
            const float p33 = __builtin_amdgcn_exp2f(accS[mi][3][3]);

            const u32x4 aw0 = { cvt_pk_bf16(p00, p01), cvt_pk_bf16(p02, p03),
                                cvt_pk_bf16(p10, p11), cvt_pk_bf16(p12, p13) };
            const u32x4 aw1 = { cvt_pk_bf16(p20, p21), cvt_pk_bf16(p22, p23),
                                cvt_pk_bf16(p30, p31), cvt_pk_bf16(p32, p33) };
            ap[mi][0] = __builtin_bit_cast(bf16x8, aw0);
            ap[mi][1] = __builtin_bit_cast(bf16x8, aw1);
        }

        // ---- PV + lsum, j-outer; bv fragments are transient ----
        __builtin_amdgcn_s_setprio(1);
        #pragma unroll
        for (int j = 0; j < 4; ++j) {
            const bf16x8 bv0 = *(const bf16x8*)&Vs[cur][16 * j + rsel][quad * 8];
            const bf16x8 bv1 = *(const bf16x8*)&Vs[cur][16 * j + rsel][32 + quad * 8];
            accO[0][j] = __builtin_amdgcn_mfma_f32_16x16x32_bf16(
                ap[0][0], bv0, accO[0][j], 0, 0, 0);
            accO[0][j] = __builtin_amdgcn_mfma_f32_16x16x32_bf16(
                ap[0][1], bv1, accO[0][j], 0, 0, 0);
            accO[1][j] = __builtin_amdgcn_mfma_f32_16x16x32_bf16(
                ap[1][0], bv0, accO[1][j], 0, 0, 0);
            accO[1][j] = __builtin_amdgcn_mfma_f32_16x16x32_bf16(
                ap[1][1], bv1, accO[1][j], 0, 0, 0);
        }
        // denominator from the SAME bf16 P (bias cancels in the ratio)
        #pragma unroll
        for (int mi = 0; mi < 2; ++mi) {
            accL[mi] = __builtin_amdgcn_mfma_f32_16x16x32_bf16(
                ap[mi][0], ones, accL[mi], 0, 0, 0);
            accL[mi] = __builtin_amdgcn_mfma_f32_16x16x32_bf16(
                ap[mi][1], ones, accL[mi], 0, 0, 0);
        }
        __builtin_amdgcn_s_setprio(0);

        // write staged tile T+1 into buf[cur^1] (vmcnt wait lands here —
        // loads issued a full tile ago; cur^1 dead since prior barrier).
        *(float4*)&Ks[cur ^ 1][crow][ccol]     = kn0;
        *(float4*)&Ks[cur ^ 1][crow][ccol + 8] = kn1;
        *(float4*)&Vs[cur ^ 1][crow][ccol]     = vn0;
        *(float4*)&Vs[cur ^ 1][crow][ccol + 8] = vn1;
        __syncthreads();               // drains ds_writes, publishes buf[cur^1]
        cur ^= 1;
    }

    // accL[mi][r] = sum for q-row 16mi+4quad+r (replicated over rsel cols)
    float* Ob = Opart + ((size_t)part * NHEADS + h) * SEQ * HD;
    float* lb = lpart + ((size_t)part * NHEADS + h) * SEQ;
    #pragma unroll
    for (int mi = 0; mi < 2; ++mi)
        #pragma unroll
        for (int r = 0; r < 4; ++r) {
            const int n = q0 + 16 * mi + 4 * quad + r;
            #pragma unroll
            for (int j = 0; j < 4; ++j)
                Ob[(size_t)n * HD + 16 * j + rsel] = accO[mi][j][r];
            if (rsel == 0) lb[n] = accL[mi][r];
        }
}

// ---------------------------------------------------------------------------
// Split-K merge: AO[n][h*64+d] = (sum_p Opart) / (sum_p l), bf16.
// ---------------------------------------------------------------------------
__global__ __launch_bounds__(256)
void merge_k(const float* __restrict__ Opart, const float* __restrict__ lpart,
             ushort* __restrict__ AO)
{
    const int idx = blockIdx.x * 256 + threadIdx.x;
    const int dg = idx & 15;
    const int n  = (idx >> 4) & (SEQ - 1);
    const int h  = idx >> 16;

    float4 o = make_float4(0.f, 0.f, 0.f, 0.f);
    float l = 0.f;
    #pragma unroll
    for (int p = 0; p < KSPLIT; ++p) {
        const float4 v = *(const float4*)&Opart[(((size_t)p * NHEADS + h) * SEQ + n) * HD + dg * 4];
        o.x += v.x; o.y += v.y; o.z += v.z; o.w += v.w;
        l += lpart[((size_t)p * NHEADS + h) * SEQ + n];
    }
    const float inv = 1.f / l;
    ushort4 w;
    w.x = f2bf(o.x * inv); w.y = f2bf(o.y * inv);
    w.z = f2bf(o.z * inv); w.w = f2bf(o.w * inv);
    *(ushort4*)&AO[(size_t)n * DIM + h * HD + dg * 4] = w;
}

// ---------------------------------------------------------------------------
// Proj GEMM: out = attnout(bf16) @ proj_wb(bf16)^T + proj_b(f32), f32 out.
// T3 1-barrier double-buffered K-loop (same as gemm_qkv).
// ---------------------------------------------------------------------------
__global__ __launch_bounds__(256)
void gemm_proj(const ushort* __restrict__ A, const ushort* __restrict__ B,
               const float* __restrict__ bias, float* __restrict__ out)
{
    constexpr int BM = 128, BN = 128, BK = 64;
    __shared__ __attribute__((aligned(16))) ushort As[2][BM][BK];
    __shared__ __attribute__((aligned(16))) ushort Bs[2][BN][BK];

    const int t    = threadIdx.x;
    const int lane = t & 63;
    const int wv   = t >> 6;
    const int wm   = (wv >> 1) * 64;
    const int wn   = (wv & 1) * 64;
    const int m0   = blockIdx.y * BM;
    const int n0   = blockIdx.x * BN;

    f32x4 acc[4][4] = {};

    const int lrow = lane >> 3;
    const int lch  = (lane & 7) * 8;

    #pragma unroll
    for (int i = 0; i < 4; ++i) {
        const int rb = i * 32 + wv * 8;
        gload16(&A[(size_t)(m0 + rb + lrow) * DIM + lch], &As[0][rb][0]);
        gload16(&B[(size_t)(n0 + rb + lrow) * DIM + lch], &Bs[0][rb][0]);
    }
    __syncthreads();

    int cur = 0;
    for (int k0 = 0; k0 < DIM; k0 += BK) {
        if (k0 + BK < DIM) {
            #pragma unroll
            for (int i = 0; i < 4; ++i) {
                const int rb = i * 32 + wv * 8;
                gload16(&A[(size_t)(m0 + rb + lrow) * DIM + k0 + BK + lch],
                        &As[cur ^ 1][rb][0]);
                gload16(&B[(size_t)(n0 + rb + lrow) * DIM + k0 + BK + lch],
                        &Bs[cur ^ 1][rb][0]);
            }
        }

        #pragma unroll
        for (int ks = 0; ks < BK; ks += 32) {
            const int koff = ks + ((lane >> 4) << 3);
            const int rs = lane & 15;
            bf16x8 af[4], bf[4];
            #pragma unroll
            for (int i = 0; i < 4; ++i) {
                af[i] = *(const bf16x8*)&As[cur][wm + i * 16 + rs][koff];
                bf[i] = *(const bf16x8*)&Bs[cur][wn + i * 16 + rs][koff];
            }
            #pragma unroll
            for (int i = 0; i < 4; ++i)
                #pragma unroll
                for (int j = 0; j < 4; ++j)
                    acc[i][j] = __builtin_amdgcn_mfma_f32_16x16x32_bf16(
                        af[i], bf[j], acc[i][j], 0, 0, 0);
        }
        __syncthreads();
        cur ^= 1;
    }

    const int rbase = m0 + wm + ((lane >> 4) << 2);
    const int cbase = n0 + wn + (lane & 15);

    #pragma unroll
    for (int j = 0; j < 4; ++j) {
        const int col = cbase + j * 16;
        const float bv = bias[col];
        #pragma unroll
        for (int i = 0; i < 4; ++i) {
            const int row0 = rbase + i * 16;
            #pragma unroll
            for (int r = 0; r < 4; ++r)
                out[(size_t)(row0 + r) * DIM + col] = acc[i][j][r] + bv;
        }
    }
}

// ---------------------------------------------------------------------------
extern "C" void kernel_launch(void* const* d_in, const int* in_sizes, int n_in,
                              void* d_out, int out_size, void* d_ws, size_t ws_size,
                              hipStream_t stream)
{
    const float* x      = (const float*)d_in[0];
    const float* qkv_w  = (const float*)d_in[1];
    const float* proj_w = (const float*)d_in[2];
    const float* proj_b = (const float*)d_in[3];

    const size_t headsz = (size_t)NHEADS * SEQ * HD;       // 3,145,728
    char* p = (char*)d_ws;
    ushort* Qb    = (ushort*)p;                 p += headsz * 2;
    ushort* Kb    = (ushort*)p;                 p += headsz * 2;
    ushort* Vp    = (ushort*)p;                 p += headsz * 2;
    ushort* AO    = (ushort*)p;                 p += (size_t)SEQ * DIM * 2;
    float*  Opart = (float*)p;                  p += (size_t)KSPLIT * headsz * 4;
    float*  lpart = (float*)p;                  p += (size_t)KSPLIT * NHEADS * SEQ * 4;
    float2* tab   = (float2*)p;                 p += (size_t)SEQ * 32 * sizeof(float2);
    ushort* xb    = (ushort*)p;                 p += (size_t)SEQ * DIM * 2;
    ushort* qwb   = (ushort*)p;                 p += (size_t)3 * DIM * DIM * 2;
    ushort* pwb   = (ushort*)p;
    float*  out   = (float*)d_out;

    prep<<<5888, 256, 0, stream>>>(x, qkv_w, proj_w, xb, qwb, pwb, tab);

    gemm_qkv<<<dim3(3 * DIM / 128, SEQ / 128), 256, 0, stream>>>(
        xb, qwb, tab, Qb, Kb, Vp);

    flash_mfma<<<dim3(SEQ / 128, NHEADS, KSPLIT), 256, 0, stream>>>(
        Qb, Kb, Vp, Opart, lpart);

    merge_k<<<(NHEADS * SEQ * 16) / 256, 256, 0, stream>>>(Opart, lpart, AO);

    gemm_proj<<<dim3(DIM / 128, SEQ / 128), 256, 0, stream>>>(
        AO, pwb, proj_b, out);
}